// Round 11
// baseline (203.916 us; speedup 1.0000x reference)
//
#include <hip/hip_runtime.h>
#include <hip/hip_bf16.h>

typedef __attribute__((ext_vector_type(8))) short short8v;
typedef __attribute__((ext_vector_type(4))) float f32x4;

__device__ __forceinline__ unsigned short f2bu(float a){
  union { __hip_bfloat16 b; unsigned short u; } cv;
  cv.b = __float2bfloat16(a);
  return cv.u;
}
// split: a = hi + lo (hi,lo bf16). Residual construction is exact for any rounding mode.
__device__ __forceinline__ void sp2(float a, unsigned short &h, unsigned short &l){
  h = f2bu(a);
  l = f2bu(a - __uint_as_float(((unsigned)h)<<16));
}
__device__ __forceinline__ float wred64(float v){
  #pragma unroll
  for(int o=32;o;o>>=1) v += __shfl_xor(v,o,64);
  return v;
}
__device__ __forceinline__ float wred32(float v){
  #pragma unroll
  for(int o=16;o;o>>=1) v += __shfl_xor(v,o,64);
  return v;
}
__device__ __forceinline__ float wmax64(float v){
  #pragma unroll
  for(int o=32;o;o>>=1) v = fmaxf(v,__shfl_xor(v,o,64));
  return v;
}

// ---------------- K2: fused msa-LN + q + attention + node (block per l) ----------------
__global__ void __launch_bounds__(256) k_ctx(
  const float* __restrict__ msa, const float* __restrict__ g_msa, const float* __restrict__ b_msa,
  const float* __restrict__ Wq, const float* __restrict__ bq,
  const float* __restrict__ Wk, const float* __restrict__ bk,
  const float* __restrict__ seq1hot, const float* __restrict__ state,
  const float* __restrict__ g_state, const float* __restrict__ b_state,
  const float* __restrict__ Wx, const float* __restrict__ bx,
  const float* __restrict__ g_node, const float* __restrict__ b_node,
  const float* __restrict__ Wm1, const float* __restrict__ xyz,
  float* __restrict__ node, float* __restrict__ nodeA, float* __restrict__ nodeB,
  float* __restrict__ ca, float* __restrict__ vv)
{
  int l = blockIdx.x, tid = threadIdx.x;
  int wave = tid>>6, lane = tid&63;
  __shared__ float ms[64][64];
  __shared__ float qs[64];
  __shared__ float logit[64];
  __shared__ float part[4][64];
  __shared__ float ins[101];
  __shared__ float nd[32];

  // fused msa layernorm: 4 threads per row (shfl_xor 1,2 stay in group)
  {
    int nn = tid>>2, qd = tid&3;
    const float* mrow = msa + ((size_t)nn*512 + (size_t)l)*64 + qd*16;
    f32x4 a[4];
    #pragma unroll
    for(int t=0;t<4;t++) a[t] = *(const f32x4*)(mrow + t*4);
    float s=0.f, ss=0.f;
    #pragma unroll
    for(int t=0;t<4;t++)
      #pragma unroll
      for(int e=0;e<4;e++){ float v=a[t][e]; s+=v; ss+=v*v; }
    s  += __shfl_xor(s,1,64);  s  += __shfl_xor(s,2,64);
    ss += __shfl_xor(ss,1,64); ss += __shfl_xor(ss,2,64);
    float mu = s*(1.f/64.f);
    float rstd = rsqrtf(ss*(1.f/64.f) - mu*mu + 1e-5f);
    #pragma unroll
    for(int t=0;t<4;t++){
      f32x4 g4 = *(const f32x4*)(g_msa + qd*16 + t*4);
      f32x4 b4 = *(const f32x4*)(b_msa + qd*16 + t*4);
      f32x4 o4;
      #pragma unroll
      for(int e=0;e<4;e++) o4[e] = (a[t][e]-mu)*rstd*g4[e] + b4[e];
      *(f32x4*)&ms[nn][qd*16 + t*4] = o4;
    }
  }
  __syncthreads();
  if(wave==0){
    float acc = bq[lane];
    for(int k=0;k<64;k++) acc += ms[0][k]*Wq[k*64+lane];
    qs[lane] = acc*0.125f;
  }
  __syncthreads();
  float qd2 = qs[lane];
  for(int it=0; it<16; ++it){
    int nn = it*4 + wave;
    float acc = bk[lane];
    for(int k2=0;k2<64;k2++) acc += ms[nn][k2]*Wk[k2*64+lane];
    float p = wred64(qd2*acc);
    if(lane==0) logit[nn] = p;
  }
  __syncthreads();
  float v  = logit[lane];
  float mx = wmax64(v);
  float e  = expf(v-mx);
  float sd = wred64(e);
  float a  = e/sd;
  float pm = 0.f;
  for(int it=0; it<16; ++it){
    int nn = it*4 + wave;
    pm += __shfl(a,nn,64)*ms[nn][lane];
  }
  part[wave][lane] = pm;
  __syncthreads();
  if(wave==0){
    ins[lane] = part[0][lane]+part[1][lane]+part[2][lane]+part[3][lane];
    if(lane<21) ins[64+lane] = seq1hot[l*21+lane];
    float sv = (lane<16)? state[l*16+lane] : 0.f;
    float mu = sv;
    #pragma unroll
    for(int o=8;o;o>>=1) mu += __shfl_xor(mu,o,64);
    mu *= (1.f/16.f);
    float dv = sv-mu;
    float var = dv*dv;
    #pragma unroll
    for(int o=8;o;o>>=1) var += __shfl_xor(var,o,64);
    var *= (1.f/16.f);
    if(lane<16) ins[85+lane] = dv*rsqrtf(var+1e-5f)*g_state[lane]+b_state[lane];

    int d = lane & 31;
    float np_ = 0.f;
    if(lane<32){
      np_ = bx[d];
      for(int c=0;c<101;c++) np_ += ins[c]*Wx[c*32+d];
    }
    float mu2 = wred32(np_)*(1.f/32.f);
    float d2  = np_-mu2;
    float v2  = wred32(d2*d2)*(1.f/32.f);
    float nv  = d2*rsqrtf(v2+1e-5f);
    if(lane<32){
      nv = nv*g_node[d]+b_node[d];
      node[l*32+d] = nv;
      nd[d] = nv;
    }
    float a2=0.f, b2=0.f;
    for(int c=0;c<32;c++){
      float x = nd[c];
      a2 += x*Wm1[c*64+lane];
      b2 += x*Wm1[(32+c)*64+lane];
    }
    nodeA[l*64+lane] = a2;
    nodeB[l*64+lane] = b2;
    if(lane<3) ca[l*3+lane] = xyz[l*9+3+lane];
    if(lane<9) vv[l*9+lane] = xyz[l*9+lane] - xyz[l*9+3+(lane%3)];
  }
}

// ---------------- K5: top-k mask, single wave per row, no barriers ----------------
__global__ void k_topk(const float* __restrict__ ca, const int* __restrict__ idx,
                       const int* __restrict__ topk_ptr, unsigned char* __restrict__ maskT){
  int i = blockIdx.x, lane = threadIdx.x;  // 64 threads
  float cx = ca[i*3], cy = ca[i*3+1], cz = ca[i*3+2];
  int idxi = idx[i];
  unsigned long long key[8];
  #pragma unroll
  for(int t=0;t<8;t++){
    int jj = t*64 + lane;
    float dx = cx-ca[jj*3], dy = cy-ca[jj*3+1], dz = cz-ca[jj*3+2];
    float dd = sqrtf(fmaxf(dx*dx+dy*dy+dz*dz, 1e-12f));
    if(jj==i) dd += 999.9f;
    key[t] = (((unsigned long long)__float_as_uint(dd))<<32) | (unsigned)jj;
    int sep = abs(idx[jj]-idxi);
    maskT[jj*512+i] = (jj!=i && sep<9) ? 1 : 0;
  }
  int kk = *topk_ptr; if(kk>512) kk = 512;
  for(int t=0;t<kk;t++){
    unsigned long long m = key[0];
    #pragma unroll
    for(int u=1;u<8;u++) m = (key[u]<m)? key[u] : m;
    #pragma unroll
    for(int o=32;o;o>>=1){
      unsigned long long o2 = __shfl_xor(m,o,64);
      m = (o2<m)? o2 : m;
    }
    int jc = (int)(m & 0xffffffffu);
    if(lane==0) maskT[jc*512+i] = 1;
    #pragma unroll
    for(int u=0;u<8;u++) if(key[u]==m) key[u] = ~0ull;
  }
}

// ---------------- K5b: fold LN gains into weights — PARALLEL: block per fragment ----------------
// wbuf frags: [0..22] hi; lo of frag f at [23+f]. 0-7 We1f, 8-13 We2f, 14-17 Wm1cf, 18-21 Wm2f, 22 Wcf.
// bbuf: [0..31] be1f, [32..63] be2f, [64..127] bm1f, [128..159] Se1 colsums
__global__ void k_fold(const float* __restrict__ We1, const float* __restrict__ be1,
                       const float* __restrict__ g_pair, const float* __restrict__ b_pair,
                       const float* __restrict__ We2, const float* __restrict__ be2,
                       const float* __restrict__ g_e1, const float* __restrict__ b_e1,
                       const float* __restrict__ Wm1, const float* __restrict__ bm1,
                       const float* __restrict__ g_e2, const float* __restrict__ b_e2,
                       const float* __restrict__ Wm2, const float* __restrict__ Wc,
                       unsigned short* __restrict__ wbuf, float* __restrict__ bbuf){
  int fidx = blockIdx.x;
  int tid  = threadIdx.x;   // 512 threads
  if(fidx < 46){
    int t = fidx*512 + tid;
    int lane = tid>>3, e = tid&7;
    int f = (fidx<23)? fidx : fidx-23;
    int krow = (lane>>4)*8 + e;
    int n = lane&15;
    float val = 0.f;
    if(f<8){
      int kt=f>>1, nt=f&1; int c=kt*32+krow, d=nt*16+n;
      val = g_pair[c]*We1[c*32+d];
    } else if(f<14){
      int f2=f-8; int kt=f2>>1, nt=f2&1; int c=kt*32+krow, d=nt*16+n;
      if(c<32)      val = g_e1[c]*We2[c*32+d];
      else if(c<69) val = We2[c*32+d];
      else          val = 0.f;
    } else if(f<18){
      int nt=f-14; int c=krow, h=nt*16+n;
      val = g_e2[c]*Wm1[(64+c)*64+h];
    } else if(f<22){
      int f2=f-18; int kt=f2>>1, nt=f2&1; int c=kt*32+krow, d=nt*16+n;
      val = Wm2[c*32+d];
    } else {
      int c=krow;
      val = (n<8)? Wc[c*8+n] : 0.f;
    }
    unsigned short h = f2bu(val);
    if(fidx<23) wbuf[t] = h;
    else {
      float fh = __uint_as_float(((unsigned)h)<<16);
      wbuf[t] = f2bu(val - fh);
    }
  } else {
    if(tid<32){
      float s = be1[tid];
      for(int c=0;c<128;c++) s += b_pair[c]*We1[c*32+tid];
      bbuf[tid]=s;
    } else if(tid<64){
      int d=tid-32; float s=be2[d];
      for(int c=0;c<32;c++) s += b_e1[c]*We2[c*32+d];
      bbuf[tid]=s;
    } else if(tid<128){
      int h=tid-64; float s=bm1[h];
      for(int c=0;c<32;c++) s += b_e2[c]*Wm1[(64+c)*64+h];
      bbuf[tid]=s;
    } else if(tid<160){
      int d=tid-128; float s=0.f;
      for(int c=0;c<128;c++) s += g_pair[c]*We1[c*32+d];
      bbuf[tid]=s;
    }
  }
}

// ---------------- K6: per-pair MLP; raw-split x + Se1-fold; grid (j, i-half); 3 waves/EU ----------------
__global__ void __launch_bounds__(256,3) k_pair_mfma(
  const float* __restrict__ pair, const unsigned short* __restrict__ wbuf,
  const float* __restrict__ bbuf, const float* __restrict__ Wm1,
  const float* __restrict__ bm2, const float* __restrict__ bc,
  const float* __restrict__ nodeA, const float* __restrict__ nodeB,
  const float* __restrict__ ca, const float* __restrict__ vv,
  const int* __restrict__ idx, const unsigned char* __restrict__ maskT,
  float* __restrict__ aggM, float* __restrict__ aggV)
{
  const int j = blockIdx.x, tid = threadIdx.x;
  const int half = blockIdx.y;
  const int base = half*256;
  const int wave = tid>>6, lane = tid&63;
  const int kg = lane>>4, n = lane&15;

  __shared__ __align__(16) unsigned short Yh[4][16*104];
  __shared__ __align__(16) unsigned short Yl[4][16*104];
  __shared__ __align__(16) unsigned short WloE[23*512];
  __shared__ float coefT[4][16*8];
  __shared__ float redM[4][32];
  __shared__ float redV[4][8];
  unsigned short* Yhw = Yh[wave];
  unsigned short* Ylw = Yl[wave];
  float* CT = coefT[wave];

  for(int t=tid; t<(23*512)/8; t+=256)
    ((uint4*)WloE)[t] = ((const uint4*)(wbuf + 23*512))[t];

  // hi weight fragments in VGPRs
  short8v wf[23];
  #pragma unroll
  for(int f=0; f<23; f++) wf[f] = *(const short8v*)(wbuf + f*512 + lane*8);

  const float be1f0 = bbuf[n],     be1f1 = bbuf[16+n];
  const float be2f0 = bbuf[32+n],  be2f1 = bbuf[48+n];
  const float se0   = bbuf[128+n], se1v  = bbuf[144+n];
  float bm1n[4], wm1d[4];
  #pragma unroll
  for(int nt=0;nt<4;nt++){
    bm1n[nt] = bbuf[64+nt*16+n] + nodeB[j*64+nt*16+n];   // bm1f + nodeBj folded
    wm1d[nt] = Wm1[96*64+nt*16+n];
  }
  const float bm2r0 = bm2[n], bm2r1 = bm2[16+n];
  const float bcr = (n<8)? bc[n] : 0.f;
  const float cjx = ca[j*3], cjy = ca[j*3+1], cjz = ca[j*3+2];
  const int idxj = idx[j];

  __syncthreads();   // WloE staged

  // zero pad cols 69..95 once (hid occupies only 0..63, never clobbers)
  for(int t=lane; t<16*27; t+=64){ int r=t/27, c=69+t-r*27; Yhw[r*104+c]=0; Ylw[r*104+c]=0; }

  float accM0=0.f, accM1=0.f;
  float accV[6]={0.f,0.f,0.f,0.f,0.f,0.f};

  // ---- prologue: load first pair row (i = base + wave*16 + n), stats + raw split ----
  short8v xh[4], xl[4];
  float sC=0.f, ssC=0.f;
  {
    const float* prow0 = pair + (((size_t)(base+wave*16+n))*512 + (size_t)j)*128;
    #pragma unroll
    for(int kt=0;kt<4;kt++){
      f32x4 a0 = *(const f32x4*)(prow0 + kt*32 + kg*8);
      f32x4 a1 = *(const f32x4*)(prow0 + kt*32 + kg*8 + 4);
      #pragma unroll
      for(int e=0;e<4;e++){
        float v0=a0[e], v1=a1[e];
        sC += v0+v1; ssC += v0*v0+v1*v1;
        unsigned short h_, l_;
        sp2(v0,h_,l_); xh[kt][e]=(short)h_;   xl[kt][e]=(short)l_;
        sp2(v1,h_,l_); xh[kt][4+e]=(short)h_; xl[kt][4+e]=(short)l_;
      }
    }
  }

  for(int i0 = base + wave*16; i0 < base + 256; i0 += 64){
    // ---- finish LN stats for current row ----
    float s=sC, ss=ssC;
    s  += __shfl_xor(s,16,64);  s  += __shfl_xor(s,32,64);
    ss += __shfl_xor(ss,16,64); ss += __shfl_xor(ss,32,64);
    float mu = s*(1.f/128.f);
    float rstd = rsqrtf(ss*(1.f/128.f) - mu*mu + 1e-5f);

    // ---- prefetch next pair row (issue early; consumed at rotate) ----
    float xn[4][8];
    const bool hasNext = (i0+64 < base+256);
    if(hasNext){
      const float* prown = pair + (((size_t)(i0+64+n))*512 + (size_t)j)*128;
      #pragma unroll
      for(int kt=0;kt<4;kt++){
        *(f32x4*)&xn[kt][0] = *(const f32x4*)(prown + kt*32 + kg*8);
        *(f32x4*)&xn[kt][4] = *(const f32x4*)(prown + kt*32 + kg*8 + 4);
      }
    }

    // ---- z = x_raw @ We1f (split 3-term); e1pre = rstd*(z - mu*Se1) + be1f; LN(32) ----
    f32x4 z0={0.f,0.f,0.f,0.f}, z1={0.f,0.f,0.f,0.f};
    #pragma unroll
    for(int kt=0;kt<4;kt++){
      short8v wlo0 = *(const short8v*)&WloE[(2*kt+0)*512 + lane*8];
      short8v wlo1 = *(const short8v*)&WloE[(2*kt+1)*512 + lane*8];
      z0 = __builtin_amdgcn_mfma_f32_16x16x32_bf16(xh[kt], wf[2*kt+0], z0, 0,0,0);
      z0 = __builtin_amdgcn_mfma_f32_16x16x32_bf16(xl[kt], wf[2*kt+0], z0, 0,0,0);
      z0 = __builtin_amdgcn_mfma_f32_16x16x32_bf16(xh[kt], wlo0,      z0, 0,0,0);
      z1 = __builtin_amdgcn_mfma_f32_16x16x32_bf16(xh[kt], wf[2*kt+1], z1, 0,0,0);
      z1 = __builtin_amdgcn_mfma_f32_16x16x32_bf16(xl[kt], wf[2*kt+1], z1, 0,0,0);
      z1 = __builtin_amdgcn_mfma_f32_16x16x32_bf16(xh[kt], wlo1,      z1, 0,0,0);
    }
    #pragma unroll
    for(int q=0;q<4;q++){
      float mu_q = __shfl(mu,   4*kg+q, 64);
      float r_q  = __shfl(rstd, 4*kg+q, 64);
      float ev0 = r_q*(z0[q] - mu_q*se0)  + be1f0;
      float ev1 = r_q*(z1[q] - mu_q*se1v) + be1f1;
      float sq  = ev0+ev1;
      float sq2 = ev0*ev0+ev1*ev1;
      #pragma unroll
      for(int o=8;o;o>>=1){ sq+=__shfl_xor(sq,o,64); sq2+=__shfl_xor(sq2,o,64); }
      float m_ = sq*(1.f/32.f);
      float rs = rsqrtf(sq2*(1.f/32.f)-m_*m_+1e-5f);
      unsigned short h0,l0,h1,l1;
      sp2((ev0-m_)*rs, h0, l0);
      sp2((ev1-m_)*rs, h1, l1);
      int r = 4*kg+q;
      Yhw[r*104 + n]    = h0;
      Yhw[r*104 + 16+n] = h1;
      Ylw[r*104 + n]    = l0;
      Ylw[r*104 + 16+n] = l1;
    }

    // ---- dist / rbf / neighbor for row (i0+n) ----
    const float* cai = ca + (i0+n)*3;
    float dxr = cjx-cai[0], dyr = cjy-cai[1], dzr = cjz-cai[2];
    float d2r = dxr*dxr+dyr*dyr+dzr*dzr;
    float dist_r = sqrtf(d2r);
    float drbf = sqrtf(fmaxf(d2r,1e-12f));
    #pragma unroll
    for(int sI=0;sI<9;sI++){
      int t = kg*9+sI;
      float u = (drbf - (float)t*(20.f/35.f))*1.8f;
      unsigned short h_, l_;
      sp2(__expf(-u*u), h_, l_);
      Yhw[n*104 + 32 + t] = h_;
      Ylw[n*104 + 32 + t] = l_;
    }
    if(kg==0){
      int sep = idxj - idx[i0+n];
      float nb = (sep>=-1 && sep<=1)?(float)sep:0.f;
      unsigned short h_, l_;
      sp2(nb, h_, l_);
      Yhw[n*104 + 68] = h_;
      Ylw[n*104 + 68] = l_;
    }

    // ---- e2 = LN(y @ We2f + be2f) ----
    short8v yh_[3], yl_[3];
    #pragma unroll
    for(int kt=0;kt<3;kt++){
      yh_[kt] = *(const short8v*)&Yhw[n*104 + kt*32 + kg*8];
      yl_[kt] = *(const short8v*)&Ylw[n*104 + kt*32 + kg*8];
    }
    f32x4 e2a0={0.f,0.f,0.f,0.f}, e2a1={0.f,0.f,0.f,0.f};
    #pragma unroll
    for(int kt=0;kt<3;kt++){
      short8v wlo0 = *(const short8v*)&WloE[(8+2*kt)*512 + lane*8];
      short8v wlo1 = *(const short8v*)&WloE[(9+2*kt)*512 + lane*8];
      e2a0 = __builtin_amdgcn_mfma_f32_16x16x32_bf16(yh_[kt], wf[8+2*kt], e2a0, 0,0,0);
      e2a0 = __builtin_amdgcn_mfma_f32_16x16x32_bf16(yl_[kt], wf[8+2*kt], e2a0, 0,0,0);
      e2a0 = __builtin_amdgcn_mfma_f32_16x16x32_bf16(yh_[kt], wlo0,      e2a0, 0,0,0);
      e2a1 = __builtin_amdgcn_mfma_f32_16x16x32_bf16(yh_[kt], wf[9+2*kt], e2a1, 0,0,0);
      e2a1 = __builtin_amdgcn_mfma_f32_16x16x32_bf16(yl_[kt], wf[9+2*kt], e2a1, 0,0,0);
      e2a1 = __builtin_amdgcn_mfma_f32_16x16x32_bf16(yh_[kt], wlo1,      e2a1, 0,0,0);
    }
    #pragma unroll
    for(int q=0;q<4;q++){
      float ev0 = e2a0[q]+be2f0;
      float ev1 = e2a1[q]+be2f1;
      float sq  = ev0+ev1;
      float sq2 = ev0*ev0+ev1*ev1;
      #pragma unroll
      for(int o=8;o;o>>=1){ sq+=__shfl_xor(sq,o,64); sq2+=__shfl_xor(sq2,o,64); }
      float m_ = sq*(1.f/32.f);
      float rs = rsqrtf(sq2*(1.f/32.f)-m_*m_+1e-5f);
      unsigned short h0,l0,h1,l1;
      sp2((ev0-m_)*rs, h0, l0);
      sp2((ev1-m_)*rs, h1, l1);
      int r = 4*kg+q;
      Yhw[r*104 + n]    = h0;
      Yhw[r*104 + 16+n] = h1;
      Ylw[r*104 + n]    = l0;
      Ylw[r*104 + 16+n] = l1;
    }

    // ---- hid = relu(e2 @ Wm1cf + nodeA_i + (bm1f+nodeBj) + dist*wm1d); H overlaid in Y cols 0..63 ----
    short8v e2Ah = *(const short8v*)&Yhw[n*104 + kg*8];
    short8v e2Al = *(const short8v*)&Ylw[n*104 + kg*8];
    float dist_q[4];
    #pragma unroll
    for(int q=0;q<4;q++) dist_q[q] = __shfl(dist_r, 4*kg+q, 64);
    #pragma unroll
    for(int nt=0;nt<4;nt++){
      short8v wlo = *(const short8v*)&WloE[(14+nt)*512 + lane*8];
      f32x4 hacc = {0.f,0.f,0.f,0.f};
      hacc = __builtin_amdgcn_mfma_f32_16x16x32_bf16(e2Ah, wf[14+nt], hacc, 0,0,0);
      hacc = __builtin_amdgcn_mfma_f32_16x16x32_bf16(e2Al, wf[14+nt], hacc, 0,0,0);
      hacc = __builtin_amdgcn_mfma_f32_16x16x32_bf16(e2Ah, wlo,       hacc, 0,0,0);
      #pragma unroll
      for(int q=0;q<4;q++){
        float t_ = hacc[q] + bm1n[nt] + dist_q[q]*wm1d[nt]
                 + nodeA[(i0+4*kg+q)*64 + nt*16+n];
        float hv = fmaxf(t_,0.f);
        unsigned short h_, l_;
        sp2(hv, h_, l_);
        Yhw[(4*kg+q)*104 + nt*16+n] = h_;
        Ylw[(4*kg+q)*104 + nt*16+n] = l_;
      }
    }

    // ---- m = relu(hid @ Wm2f + bm2) ----
    short8v hAh[2], hAl[2];
    #pragma unroll
    for(int kt=0;kt<2;kt++){
      hAh[kt] = *(const short8v*)&Yhw[n*104 + kt*32 + kg*8];
      hAl[kt] = *(const short8v*)&Ylw[n*104 + kt*32 + kg*8];
    }
    f32x4 ma0={0.f,0.f,0.f,0.f}, ma1={0.f,0.f,0.f,0.f};
    #pragma unroll
    for(int kt=0;kt<2;kt++){
      short8v wlo0 = *(const short8v*)&WloE[(18+2*kt)*512 + lane*8];
      short8v wlo1 = *(const short8v*)&WloE[(19+2*kt)*512 + lane*8];
      ma0 = __builtin_amdgcn_mfma_f32_16x16x32_bf16(hAh[kt], wf[18+2*kt], ma0, 0,0,0);
      ma0 = __builtin_amdgcn_mfma_f32_16x16x32_bf16(hAl[kt], wf[18+2*kt], ma0, 0,0,0);
      ma0 = __builtin_amdgcn_mfma_f32_16x16x32_bf16(hAh[kt], wlo0,       ma0, 0,0,0);
      ma1 = __builtin_amdgcn_mfma_f32_16x16x32_bf16(hAh[kt], wf[19+2*kt], ma1, 0,0,0);
      ma1 = __builtin_amdgcn_mfma_f32_16x16x32_bf16(hAl[kt], wf[19+2*kt], ma1, 0,0,0);
      ma1 = __builtin_amdgcn_mfma_f32_16x16x32_bf16(hAh[kt], wlo1,       ma1, 0,0,0);
    }
    float mk[4];
    #pragma unroll
    for(int q=0;q<4;q++) mk[q] = (float)maskT[j*512 + i0+4*kg+q];
    #pragma unroll
    for(int q=0;q<4;q++){
      float mv0 = fmaxf(ma0[q]+bm2r0, 0.f);
      float mv1 = fmaxf(ma1[q]+bm2r1, 0.f);
      accM0 += mk[q]*mv0;
      accM1 += mk[q]*mv1;
      unsigned short h0,l0,h1,l1;
      sp2(mv0, h0, l0);
      sp2(mv1, h1, l1);
      int r = 4*kg+q;
      Yhw[r*104 + n]    = h0;
      Yhw[r*104 + 16+n] = h1;
      Ylw[r*104 + n]    = l0;
      Ylw[r*104 + 16+n] = l1;
    }

    // ---- coef = m @ Wcf + bc ----
    short8v mAh = *(const short8v*)&Yhw[n*104 + kg*8];
    short8v mAl = *(const short8v*)&Ylw[n*104 + kg*8];
    short8v wloC = *(const short8v*)&WloE[22*512 + lane*8];
    f32x4 cf = {0.f,0.f,0.f,0.f};
    cf = __builtin_amdgcn_mfma_f32_16x16x32_bf16(mAh, wf[22], cf, 0,0,0);
    cf = __builtin_amdgcn_mfma_f32_16x16x32_bf16(mAl, wf[22], cf, 0,0,0);
    cf = __builtin_amdgcn_mfma_f32_16x16x32_bf16(mAh, wloC,  cf, 0,0,0);
    if(n<8){
      #pragma unroll
      for(int q=0;q<4;q++) CT[(4*kg+q)*8+n] = cf[q]+bcr;
    }
    f32x4 cA = *(const f32x4*)&CT[n*8];
    f32x4 cB = *(const f32x4*)&CT[n*8+4];

    // ---- vmsg accumulation for row (i0+n) ----
    float mkr = (float)maskT[j*512 + i0+n];
    const float* vr = vv + (i0+n)*9;
    float v00=vr[0], v01=vr[1], v02=vr[2];
    float v10=vr[3], v11=vr[4], v12=vr[5];
    float v20=vr[6], v21=vr[7], v22=vr[8];
    accV[0] += mkr*(cA[0]*dxr + cA[1]*v00 + cA[2]*v10 + cA[3]*v20);
    accV[1] += mkr*(cA[0]*dyr + cA[1]*v01 + cA[2]*v11 + cA[3]*v21);
    accV[2] += mkr*(cA[0]*dzr + cA[1]*v02 + cA[2]*v12 + cA[3]*v22);
    accV[3] += mkr*(cB[0]*dxr + cB[1]*v00 + cB[2]*v10 + cB[3]*v20);
    accV[4] += mkr*(cB[0]*dyr + cB[1]*v01 + cB[2]*v11 + cB[3]*v21);
    accV[5] += mkr*(cB[0]*dzr + cB[1]*v02 + cB[2]*v12 + cB[3]*v22);

    // ---- rotate: stats + raw split of prefetched row (vmcnt wait lands here) ----
    if(hasNext){
      float sN=0.f, ssN=0.f;
      #pragma unroll
      for(int kt=0;kt<4;kt++){
        #pragma unroll
        for(int e=0;e<8;e++){
          float v = xn[kt][e];
          sN += v; ssN += v*v;
          unsigned short h_, l_;
          sp2(v, h_, l_);
          xh[kt][e] = (short)h_;
          xl[kt][e] = (short)l_;
        }
      }
      sC = sN; ssC = ssN;
    }
  }

  // ---- reductions ----
  accM0 += __shfl_xor(accM0,16,64); accM0 += __shfl_xor(accM0,32,64);
  accM1 += __shfl_xor(accM1,16,64); accM1 += __shfl_xor(accM1,32,64);
  #pragma unroll
  for(int c=0;c<6;c++){
    #pragma unroll
    for(int o=8;o;o>>=1) accV[c] += __shfl_xor(accV[c],o,64);
  }
  if(lane<16){ redM[wave][n] = accM0; redM[wave][16+n] = accM1; }
  if(lane==0){
    #pragma unroll
    for(int c=0;c<6;c++) redV[wave][c]=accV[c];
  }
  __syncthreads();
  float* aggMh = aggM + (size_t)half*512*32;
  float* aggVh = aggV + (size_t)half*512*6;
  if(tid<32) aggMh[j*32+tid] = redM[0][tid]+redM[1][tid]+redM[2][tid]+redM[3][tid];
  if(tid>=64 && tid<70){
    int c = tid-64;
    aggVh[j*6+c] = redV[0][c]+redV[1][c]+redV[2][c]+redV[3][c];
  }
}

// ---------------- K7: state_out + SE(3) frame update (sums i-halves) ----------------
__global__ void k_final(const float* __restrict__ node, const float* __restrict__ aggM,
                        const float* __restrict__ aggV, const float* __restrict__ Wh,
                        const float* __restrict__ bh, const float* __restrict__ Wv,
                        const float* __restrict__ ca, const float* __restrict__ vvb,
                        float* __restrict__ out){
  int l = blockIdx.x, lane = threadIdx.x;
  if(lane<16){
    float acc = bh[lane];
    for(int c=0;c<32;c++) acc += node[l*32+c]*Wh[c*16+lane];
    for(int c=0;c<32;c++) acc += (aggM[l*32+c]+aggM[512*32+l*32+c])*Wh[(32+c)*16+lane];
    out[4608 + l*16 + lane] = acc;
  }
  if(lane<9){
    int a = lane/3, vd = lane%3;
    float T[3], R[3];
    for(int q2=0;q2<3;q2++){
      float v0 = vvb[l*9+q2], v1 = vvb[l*9+3+q2], v2 = vvb[l*9+6+q2];
      float av0 = aggV[l*6+q2]   + aggV[512*6+l*6+q2];
      float av1 = aggV[l*6+3+q2] + aggV[512*6+l*6+3+q2];
      T[q2] = av0 + Wv[0]*v0 + Wv[1]*v1 + Wv[2]*v2;
      R[q2] = av1 + Wv[3]*v0 + Wv[4]*v1 + Wv[5]*v2;
    }
    float ang = sqrtf(R[0]*R[0]+R[1]*R[1]+R[2]*R[2]);
    float inv = 1.f/(ang+1e-5f);
    float Rv0=R[0]*inv, Rv1=R[1]*inv, Rv2=R[2]*inv;
    float va0=vvb[l*9+a*3+0], va1=vvb[l*9+a*3+1], va2=vvb[l*9+a*3+2];
    float Rdv = Rv0*va0+Rv1*va1+Rv2*va2;
    float Rvv[3]={Rv0,Rv1,Rv2};
    float vaa[3]={va0,va1,va2};
    float Rxv = Rvv[(vd+1)%3]*vaa[(vd+2)%3] - Rvv[(vd+2)%3]*vaa[(vd+1)%3];
    float vperp = vaa[vd] - Rvv[vd]*Rdv;
    float upar  = Rvv[vd]*Rdv;
    float cc = cosf(ang), ss = sinf(ang);
    float vnew = vperp*cc + Rxv*ss + upar;
    out[l*9+a*3+vd] = vnew + ca[l*3+vd] + T[vd];
  }
}

extern "C" void kernel_launch(void* const* d_in, const int* in_sizes, int n_in,
                              void* d_out, int out_size, void* d_ws, size_t ws_size,
                              hipStream_t stream) {
  const float* msa    = (const float*)d_in[0];
  const float* pair   = (const float*)d_in[1];
  const float* xyz    = (const float*)d_in[2];
  const float* state  = (const float*)d_in[3];
  const float* seq1hot= (const float*)d_in[4];
  const int*   idx    = (const int*)d_in[5];
  const int*   topk   = (const int*)d_in[6];
  const float* g_msa  = (const float*)d_in[7];  const float* b_msa  = (const float*)d_in[8];
  const float* g_pair = (const float*)d_in[9];  const float* b_pair = (const float*)d_in[10];
  const float* g_state= (const float*)d_in[11]; const float* b_state= (const float*)d_in[12];
  const float* Wq = (const float*)d_in[13]; const float* bq = (const float*)d_in[14];
  const float* Wk = (const float*)d_in[15]; const float* bk = (const float*)d_in[16];
  const float* Wx = (const float*)d_in[17]; const float* bx = (const float*)d_in[18];
  const float* We1= (const float*)d_in[19]; const float* be1= (const float*)d_in[20];
  const float* We2= (const float*)d_in[21]; const float* be2= (const float*)d_in[22];
  const float* g_node=(const float*)d_in[23]; const float* b_node=(const float*)d_in[24];
  const float* g_e1 = (const float*)d_in[25]; const float* b_e1 = (const float*)d_in[26];
  const float* g_e2 = (const float*)d_in[27]; const float* b_e2 = (const float*)d_in[28];
  const float* Wm1= (const float*)d_in[29]; const float* bm1= (const float*)d_in[30];
  const float* Wm2= (const float*)d_in[31]; const float* bm2= (const float*)d_in[32];
  const float* Wc = (const float*)d_in[33]; const float* bc = (const float*)d_in[34];
  const float* Wh = (const float*)d_in[35]; const float* bh = (const float*)d_in[36];
  const float* Wv = (const float*)d_in[37];
  float* out = (float*)d_out;

  float* ws = (float*)d_ws;
  float* node   = ws; ws += 512*32;
  float* nodeA  = ws; ws += 512*64;
  float* nodeB  = ws; ws += 512*64;
  float* cab    = ws; ws += 512*3;
  float* vvb    = ws; ws += 512*9;
  float* aggM   = ws; ws += 2*512*32;
  float* aggV   = ws; ws += 2*512*6;
  float* bbuf   = ws; ws += 160;
  unsigned short* wbuf = (unsigned short*)ws; ws += (46*512)/2 + 8;
  unsigned char* maskT = (unsigned char*)ws;

  k_fold<<<47,512,0,stream>>>(We1,be1,g_pair,b_pair,We2,be2,g_e1,b_e1,Wm1,bm1,g_e2,b_e2,Wm2,Wc,wbuf,bbuf);
  k_ctx<<<512,256,0,stream>>>(msa,g_msa,b_msa,Wq,bq,Wk,bk,seq1hot,state,g_state,b_state,
                              Wx,bx,g_node,b_node,Wm1,xyz,node,nodeA,nodeB,cab,vvb);
  k_topk<<<512,64,0,stream>>>(cab,idx,topk,maskT);
  k_pair_mfma<<<dim3(512,2),256,0,stream>>>(pair,wbuf,bbuf,Wm1,bm2,bc,nodeA,nodeB,cab,vvb,idx,maskT,aggM,aggV);
  k_final<<<512,64,0,stream>>>(node,aggM,aggV,Wh,bh,Wv,cab,vvb,out);
}

// Round 12
// 113.169 us; speedup vs baseline: 1.8019x; 1.8019x over previous
//
#include <hip/hip_runtime.h>
#include <hip/hip_bf16.h>

typedef __attribute__((ext_vector_type(8))) short short8v;
typedef __attribute__((ext_vector_type(4))) float f32x4;

__device__ __forceinline__ unsigned short f2bu(float a){
  union { __hip_bfloat16 b; unsigned short u; } cv;
  cv.b = __float2bfloat16(a);
  return cv.u;
}
// split: a = hi + lo (hi,lo bf16). Residual construction is exact for any rounding mode.
__device__ __forceinline__ void sp2(float a, unsigned short &h, unsigned short &l){
  h = f2bu(a);
  l = f2bu(a - __uint_as_float(((unsigned)h)<<16));
}
__device__ __forceinline__ float wred64(float v){
  #pragma unroll
  for(int o=32;o;o>>=1) v += __shfl_xor(v,o,64);
  return v;
}
__device__ __forceinline__ float wred32(float v){
  #pragma unroll
  for(int o=16;o;o>>=1) v += __shfl_xor(v,o,64);
  return v;
}
__device__ __forceinline__ float wmax64(float v){
  #pragma unroll
  for(int o=32;o;o>>=1) v = fmaxf(v,__shfl_xor(v,o,64));
  return v;
}

// ---------------- K2: fused msa-LN + q + attention + node + topk (block per l) ----------------
__global__ void __launch_bounds__(256) k_ctx(
  const float* __restrict__ msa, const float* __restrict__ g_msa, const float* __restrict__ b_msa,
  const float* __restrict__ Wq, const float* __restrict__ bq,
  const float* __restrict__ Wk, const float* __restrict__ bk,
  const float* __restrict__ seq1hot, const float* __restrict__ state,
  const float* __restrict__ g_state, const float* __restrict__ b_state,
  const float* __restrict__ Wx, const float* __restrict__ bx,
  const float* __restrict__ g_node, const float* __restrict__ b_node,
  const float* __restrict__ Wm1,
  float* __restrict__ node, float* __restrict__ nodeA, float* __restrict__ nodeB,
  const float* __restrict__ ca, const int* __restrict__ idx,
  const int* __restrict__ topk_ptr, unsigned char* __restrict__ maskT)
{
  int l = blockIdx.x, tid = threadIdx.x;
  int wave = tid>>6, lane = tid&63;
  __shared__ float ms[64][64];
  __shared__ float qs[64];
  __shared__ float logit[64];
  __shared__ float part[4][64];
  __shared__ float ins[101];
  __shared__ float nd[32];

  // fused msa layernorm: 4 threads per row (shfl_xor 1,2 stay in group)
  {
    int nn = tid>>2, qd = tid&3;
    const float* mrow = msa + ((size_t)nn*512 + (size_t)l)*64 + qd*16;
    f32x4 a[4];
    #pragma unroll
    for(int t=0;t<4;t++) a[t] = *(const f32x4*)(mrow + t*4);
    float s=0.f, ss=0.f;
    #pragma unroll
    for(int t=0;t<4;t++)
      #pragma unroll
      for(int e=0;e<4;e++){ float v=a[t][e]; s+=v; ss+=v*v; }
    s  += __shfl_xor(s,1,64);  s  += __shfl_xor(s,2,64);
    ss += __shfl_xor(ss,1,64); ss += __shfl_xor(ss,2,64);
    float mu = s*(1.f/64.f);
    float rstd = rsqrtf(ss*(1.f/64.f) - mu*mu + 1e-5f);
    #pragma unroll
    for(int t=0;t<4;t++){
      f32x4 g4 = *(const f32x4*)(g_msa + qd*16 + t*4);
      f32x4 b4 = *(const f32x4*)(b_msa + qd*16 + t*4);
      f32x4 o4;
      #pragma unroll
      for(int e=0;e<4;e++) o4[e] = (a[t][e]-mu)*rstd*g4[e] + b4[e];
      *(f32x4*)&ms[nn][qd*16 + t*4] = o4;
    }
  }
  __syncthreads();
  if(wave==0){
    float acc = bq[lane];
    for(int k=0;k<64;k++) acc += ms[0][k]*Wq[k*64+lane];
    qs[lane] = acc*0.125f;
  }
  __syncthreads();
  float qd2 = qs[lane];
  for(int it=0; it<16; ++it){
    int nn = it*4 + wave;
    float acc = bk[lane];
    for(int k2=0;k2<64;k2++) acc += ms[nn][k2]*Wk[k2*64+lane];
    float p = wred64(qd2*acc);
    if(lane==0) logit[nn] = p;
  }
  __syncthreads();
  float v  = logit[lane];
  float mx = wmax64(v);
  float e  = expf(v-mx);
  float sd = wred64(e);
  float a  = e/sd;
  float pm = 0.f;
  for(int it=0; it<16; ++it){
    int nn = it*4 + wave;
    pm += __shfl(a,nn,64)*ms[nn][lane];
  }
  part[wave][lane] = pm;
  __syncthreads();
  if(wave==0){
    ins[lane] = part[0][lane]+part[1][lane]+part[2][lane]+part[3][lane];
    if(lane<21) ins[64+lane] = seq1hot[l*21+lane];
    float sv = (lane<16)? state[l*16+lane] : 0.f;
    float mu = sv;
    #pragma unroll
    for(int o=8;o;o>>=1) mu += __shfl_xor(mu,o,64);
    mu *= (1.f/16.f);
    float dv = sv-mu;
    float var = dv*dv;
    #pragma unroll
    for(int o=8;o;o>>=1) var += __shfl_xor(var,o,64);
    var *= (1.f/16.f);
    if(lane<16) ins[85+lane] = dv*rsqrtf(var+1e-5f)*g_state[lane]+b_state[lane];

    int d = lane & 31;
    float np_ = 0.f;
    if(lane<32){
      np_ = bx[d];
      for(int c=0;c<101;c++) np_ += ins[c]*Wx[c*32+d];
    }
    float mu2 = wred32(np_)*(1.f/32.f);
    float d2  = np_-mu2;
    float v2  = wred32(d2*d2)*(1.f/32.f);
    float nv  = d2*rsqrtf(v2+1e-5f);
    if(lane<32){
      nv = nv*g_node[d]+b_node[d];
      node[l*32+d] = nv;
      nd[d] = nv;
    }
    float a2=0.f, b2=0.f;
    for(int c=0;c<32;c++){
      float x = nd[c];
      a2 += x*Wm1[c*64+lane];
      b2 += x*Wm1[(32+c)*64+lane];
    }
    nodeA[l*64+lane] = a2;
    nodeB[l*64+lane] = b2;
  } else if(wave==1){
    // ---- top-k mask for row l (ca precomputed by k_fold) ----
    int i = l;
    float cx = ca[i*3], cy = ca[i*3+1], cz = ca[i*3+2];
    int idxi = idx[i];
    unsigned long long key[8];
    #pragma unroll
    for(int t=0;t<8;t++){
      int jj = t*64 + lane;
      float dx = cx-ca[jj*3], dy = cy-ca[jj*3+1], dz = cz-ca[jj*3+2];
      float dd = sqrtf(fmaxf(dx*dx+dy*dy+dz*dz, 1e-12f));
      if(jj==i) dd += 999.9f;
      key[t] = (((unsigned long long)__float_as_uint(dd))<<32) | (unsigned)jj;
      int sep = abs(idx[jj]-idxi);
      maskT[jj*512+i] = (jj!=i && sep<9) ? 1 : 0;
    }
    int kk = *topk_ptr; if(kk>512) kk = 512;
    for(int t=0;t<kk;t++){
      unsigned long long m = key[0];
      #pragma unroll
      for(int u=1;u<8;u++) m = (key[u]<m)? key[u] : m;
      #pragma unroll
      for(int o=32;o;o>>=1){
        unsigned long long o2 = __shfl_xor(m,o,64);
        m = (o2<m)? o2 : m;
      }
      int jc = (int)(m & 0xffffffffu);
      if(lane==0) maskT[jc*512+i] = 1;
      #pragma unroll
      for(int u=0;u<8;u++) if(key[u]==m) key[u] = ~0ull;
    }
  }
}

// ---------------- K5b: fold LN gains into weights — PARALLEL; block 47 computes ca/vv ----------------
// wbuf frags: [0..22] hi; lo of frag f at [23+f]. 0-7 We1f, 8-13 We2f, 14-17 Wm1cf, 18-21 Wm2f, 22 Wcf.
// bbuf: [0..31] be1f, [32..63] be2f, [64..127] bm1f
__global__ void k_fold(const float* __restrict__ We1, const float* __restrict__ be1,
                       const float* __restrict__ g_pair, const float* __restrict__ b_pair,
                       const float* __restrict__ We2, const float* __restrict__ be2,
                       const float* __restrict__ g_e1, const float* __restrict__ b_e1,
                       const float* __restrict__ Wm1, const float* __restrict__ bm1,
                       const float* __restrict__ g_e2, const float* __restrict__ b_e2,
                       const float* __restrict__ Wm2, const float* __restrict__ Wc,
                       const float* __restrict__ xyz,
                       unsigned short* __restrict__ wbuf, float* __restrict__ bbuf,
                       float* __restrict__ ca, float* __restrict__ vv){
  int fidx = blockIdx.x;
  int tid  = threadIdx.x;   // 512 threads
  if(fidx < 46){
    int t = fidx*512 + tid;
    int lane = tid>>3, e = tid&7;
    int f = (fidx<23)? fidx : fidx-23;
    int krow = (lane>>4)*8 + e;
    int n = lane&15;
    float val = 0.f;
    if(f<8){
      int kt=f>>1, nt=f&1; int c=kt*32+krow, d=nt*16+n;
      val = g_pair[c]*We1[c*32+d];
    } else if(f<14){
      int f2=f-8; int kt=f2>>1, nt=f2&1; int c=kt*32+krow, d=nt*16+n;
      if(c<32)      val = g_e1[c]*We2[c*32+d];
      else if(c<69) val = We2[c*32+d];
      else          val = 0.f;
    } else if(f<18){
      int nt=f-14; int c=krow, h=nt*16+n;
      val = g_e2[c]*Wm1[(64+c)*64+h];
    } else if(f<22){
      int f2=f-18; int kt=f2>>1, nt=f2&1; int c=kt*32+krow, d=nt*16+n;
      val = Wm2[c*32+d];
    } else {
      int c=krow;
      val = (n<8)? Wc[c*8+n] : 0.f;
    }
    unsigned short h = f2bu(val);
    if(fidx<23) wbuf[t] = h;
    else {
      float fh = __uint_as_float(((unsigned)h)<<16);
      wbuf[t] = f2bu(val - fh);
    }
  } else if(fidx == 46){
    if(tid<32){
      float s = be1[tid];
      for(int c=0;c<128;c++) s += b_pair[c]*We1[c*32+tid];
      bbuf[tid]=s;
    } else if(tid<64){
      int d=tid-32; float s=be2[d];
      for(int c=0;c<32;c++) s += b_e1[c]*We2[c*32+d];
      bbuf[tid]=s;
    } else if(tid<128){
      int h=tid-64; float s=bm1[h];
      for(int c=0;c<32;c++) s += b_e2[c]*Wm1[(64+c)*64+h];
      bbuf[tid]=s;
    }
  } else {
    // ca / vv from xyz (thread per residue)
    int l = tid;
    float c0=xyz[l*9+3], c1=xyz[l*9+4], c2=xyz[l*9+5];
    ca[l*3+0]=c0; ca[l*3+1]=c1; ca[l*3+2]=c2;
    #pragma unroll
    for(int a2=0;a2<3;a2++){
      vv[l*9+a2*3+0]=xyz[l*9+a2*3+0]-c0;
      vv[l*9+a2*3+1]=xyz[l*9+a2*3+1]-c1;
      vv[l*9+a2*3+2]=xyz[l*9+a2*3+2]-c2;
    }
  }
}

// ---------------- K6: per-pair MLP via split-bf16 MFMA (R10 config + early side loads) ----------------
__global__ void __launch_bounds__(256,2) k_pair_mfma(
  const float* __restrict__ pair, const unsigned short* __restrict__ wbuf,
  const float* __restrict__ bbuf, const float* __restrict__ Wm1,
  const float* __restrict__ bm2, const float* __restrict__ bc,
  const float* __restrict__ nodeA, const float* __restrict__ nodeB,
  const float* __restrict__ ca, const float* __restrict__ vv,
  const int* __restrict__ idx, const unsigned char* __restrict__ maskT,
  float* __restrict__ aggM, float* __restrict__ aggV)
{
  const int j = blockIdx.x, tid = threadIdx.x;
  const int wave = tid>>6, lane = tid&63;
  const int kg = lane>>4, n = lane&15;

  __shared__ __align__(16) unsigned short Yh[4][16*104];
  __shared__ __align__(16) unsigned short Yl[4][16*104];
  __shared__ __align__(16) unsigned short WloE[23*512];
  __shared__ float coefT[4][16*8];
  __shared__ float redM[4][32];
  __shared__ float redV[4][8];
  unsigned short* Yhw = Yh[wave];
  unsigned short* Ylw = Yl[wave];
  float* CT = coefT[wave];

  for(int t=tid; t<(23*512)/8; t+=256)
    ((uint4*)WloE)[t] = ((const uint4*)(wbuf + 23*512))[t];

  // hi weight fragments in VGPRs
  short8v wf[23];
  #pragma unroll
  for(int f=0; f<23; f++) wf[f] = *(const short8v*)(wbuf + f*512 + lane*8);

  const float be1f0 = bbuf[n],     be1f1 = bbuf[16+n];
  const float be2f0 = bbuf[32+n],  be2f1 = bbuf[48+n];
  float bm1n[4], wm1d[4];
  #pragma unroll
  for(int nt=0;nt<4;nt++){
    bm1n[nt] = bbuf[64+nt*16+n] + nodeB[j*64+nt*16+n];   // bm1f + nodeBj folded
    wm1d[nt] = Wm1[96*64+nt*16+n];
  }
  const float bm2r0 = bm2[n], bm2r1 = bm2[16+n];
  const float bcr = (n<8)? bc[n] : 0.f;
  const float cjx = ca[j*3], cjy = ca[j*3+1], cjz = ca[j*3+2];
  const int idxj = idx[j];

  __syncthreads();   // WloE staged

  // zero pad cols 69..95 once (hid occupies only 0..63, never clobbers)
  for(int t=lane; t<16*27; t+=64){ int r=t/27, c=69+t-r*27; Yhw[r*104+c]=0; Ylw[r*104+c]=0; }

  float accM0=0.f, accM1=0.f;
  float accV[6]={0.f,0.f,0.f,0.f,0.f,0.f};

  // ---- preload first pair row (i = wave*16 + n) ----
  float x[4][8];
  {
    const float* prow0 = pair + (((size_t)(wave*16+n))*512 + (size_t)j)*128;
    #pragma unroll
    for(int kt=0;kt<4;kt++){
      *(f32x4*)&x[kt][0] = *(const f32x4*)(prow0 + kt*32 + kg*8);
      *(f32x4*)&x[kt][4] = *(const f32x4*)(prow0 + kt*32 + kg*8 + 4);
    }
  }

  for(int i0 = wave*16; i0 < 512; i0 += 64){
    // ---- LN stats in f32 ----
    float s=0.f, ss=0.f;
    #pragma unroll
    for(int kt=0;kt<4;kt++)
      #pragma unroll
      for(int e=0;e<8;e++){ float xv=x[kt][e]; s+=xv; ss+=xv*xv; }
    s  += __shfl_xor(s,16,64);  s  += __shfl_xor(s,32,64);
    ss += __shfl_xor(ss,16,64); ss += __shfl_xor(ss,32,64);
    float mu = s*(1.f/128.f);
    float rstd = rsqrtf(ss*(1.f/128.f) - mu*mu + 1e-5f);

    // ---- prefetch next pair row (T14: issue early, consume at rotate) ----
    float xn[4][8];
    const bool hasNext = (i0+64 < 512);
    if(hasNext){
      const float* prown = pair + (((size_t)(i0+64+n))*512 + (size_t)j)*128;
      #pragma unroll
      for(int kt=0;kt<4;kt++){
        *(f32x4*)&xn[kt][0] = *(const f32x4*)(prown + kt*32 + kg*8);
        *(f32x4*)&xn[kt][4] = *(const f32x4*)(prown + kt*32 + kg*8 + 4);
      }
    }

    // ---- EARLY: issue side-data loads for THIS iteration (consumed in hid/vmsg) ----
    float na[4][4];
    #pragma unroll
    for(int q=0;q<4;q++)
      #pragma unroll
      for(int nt=0;nt<4;nt++)
        na[nt][q] = nodeA[(size_t)(i0+4*kg+q)*64 + nt*16+n];
    float mk[4];
    #pragma unroll
    for(int q=0;q<4;q++) mk[q] = (float)maskT[j*512 + i0+4*kg+q];
    float mkr = (float)maskT[j*512 + i0+n];
    const float* vr = vv + (i0+n)*9;
    float v00=vr[0], v01=vr[1], v02=vr[2];
    float v10=vr[3], v11=vr[4], v12=vr[5];
    float v20=vr[6], v21=vr[7], v22=vr[8];
    const float* cai = ca + (i0+n)*3;
    float cix=cai[0], ciy=cai[1], ciz=cai[2];
    int idxi_r = idx[i0+n];

    // ---- normalize + split hi/lo (VALU work hides the loads above) ----
    short8v xh[4], xl[4];
    #pragma unroll
    for(int kt=0;kt<4;kt++){
      #pragma unroll
      for(int e=0;e<8;e++){
        unsigned short h_, l_;
        sp2((x[kt][e]-mu)*rstd, h_, l_);
        xh[kt][e] = (short)h_;
        xl[kt][e] = (short)l_;
      }
    }

    // ---- e1 = LN(x_hat @ We1f + be1f), split matmul ----
    f32x4 z0={0.f,0.f,0.f,0.f}, z1={0.f,0.f,0.f,0.f};
    #pragma unroll
    for(int kt=0;kt<4;kt++){
      short8v wlo0 = *(const short8v*)&WloE[(2*kt+0)*512 + lane*8];
      short8v wlo1 = *(const short8v*)&WloE[(2*kt+1)*512 + lane*8];
      z0 = __builtin_amdgcn_mfma_f32_16x16x32_bf16(xh[kt], wf[2*kt+0], z0, 0,0,0);
      z0 = __builtin_amdgcn_mfma_f32_16x16x32_bf16(xl[kt], wf[2*kt+0], z0, 0,0,0);
      z0 = __builtin_amdgcn_mfma_f32_16x16x32_bf16(xh[kt], wlo0,      z0, 0,0,0);
      z1 = __builtin_amdgcn_mfma_f32_16x16x32_bf16(xh[kt], wf[2*kt+1], z1, 0,0,0);
      z1 = __builtin_amdgcn_mfma_f32_16x16x32_bf16(xl[kt], wf[2*kt+1], z1, 0,0,0);
      z1 = __builtin_amdgcn_mfma_f32_16x16x32_bf16(xh[kt], wlo1,      z1, 0,0,0);
    }
    #pragma unroll
    for(int q=0;q<4;q++){
      float ev0 = z0[q] + be1f0;
      float ev1 = z1[q] + be1f1;
      float sq  = ev0+ev1;
      float sq2 = ev0*ev0+ev1*ev1;
      #pragma unroll
      for(int o=8;o;o>>=1){ sq+=__shfl_xor(sq,o,64); sq2+=__shfl_xor(sq2,o,64); }
      float m_ = sq*(1.f/32.f);
      float rs = rsqrtf(sq2*(1.f/32.f)-m_*m_+1e-5f);
      unsigned short h0,l0,h1,l1;
      sp2((ev0-m_)*rs, h0, l0);
      sp2((ev1-m_)*rs, h1, l1);
      int r = 4*kg+q;
      Yhw[r*104 + n]    = h0;
      Yhw[r*104 + 16+n] = h1;
      Ylw[r*104 + n]    = l0;
      Ylw[r*104 + 16+n] = l1;
    }

    // ---- dist / rbf / neighbor for row (i0+n) ----
    float dxr = cjx-cix, dyr = cjy-ciy, dzr = cjz-ciz;
    float d2r = dxr*dxr+dyr*dyr+dzr*dzr;
    float dist_r = sqrtf(d2r);
    float drbf = sqrtf(fmaxf(d2r,1e-12f));
    #pragma unroll
    for(int sI=0;sI<9;sI++){
      int t = kg*9+sI;
      float u = (drbf - (float)t*(20.f/35.f))*1.8f;
      unsigned short h_, l_;
      sp2(__expf(-u*u), h_, l_);
      Yhw[n*104 + 32 + t] = h_;
      Ylw[n*104 + 32 + t] = l_;
    }
    if(kg==0){
      int sep = idxj - idxi_r;
      float nb = (sep>=-1 && sep<=1)?(float)sep:0.f;
      unsigned short h_, l_;
      sp2(nb, h_, l_);
      Yhw[n*104 + 68] = h_;
      Ylw[n*104 + 68] = l_;
    }

    // ---- e2 = LN(y @ We2f + be2f) ----
    short8v yh_[3], yl_[3];
    #pragma unroll
    for(int kt=0;kt<3;kt++){
      yh_[kt] = *(const short8v*)&Yhw[n*104 + kt*32 + kg*8];
      yl_[kt] = *(const short8v*)&Ylw[n*104 + kt*32 + kg*8];
    }
    f32x4 e2a0={0.f,0.f,0.f,0.f}, e2a1={0.f,0.f,0.f,0.f};
    #pragma unroll
    for(int kt=0;kt<3;kt++){
      short8v wlo0 = *(const short8v*)&WloE[(8+2*kt)*512 + lane*8];
      short8v wlo1 = *(const short8v*)&WloE[(9+2*kt)*512 + lane*8];
      e2a0 = __builtin_amdgcn_mfma_f32_16x16x32_bf16(yh_[kt], wf[8+2*kt], e2a0, 0,0,0);
      e2a0 = __builtin_amdgcn_mfma_f32_16x16x32_bf16(yl_[kt], wf[8+2*kt], e2a0, 0,0,0);
      e2a0 = __builtin_amdgcn_mfma_f32_16x16x32_bf16(yh_[kt], wlo0,      e2a0, 0,0,0);
      e2a1 = __builtin_amdgcn_mfma_f32_16x16x32_bf16(yh_[kt], wf[9+2*kt], e2a1, 0,0,0);
      e2a1 = __builtin_amdgcn_mfma_f32_16x16x32_bf16(yl_[kt], wf[9+2*kt], e2a1, 0,0,0);
      e2a1 = __builtin_amdgcn_mfma_f32_16x16x32_bf16(yh_[kt], wlo1,      e2a1, 0,0,0);
    }
    #pragma unroll
    for(int q=0;q<4;q++){
      float ev0 = e2a0[q]+be2f0;
      float ev1 = e2a1[q]+be2f1;
      float sq  = ev0+ev1;
      float sq2 = ev0*ev0+ev1*ev1;
      #pragma unroll
      for(int o=8;o;o>>=1){ sq+=__shfl_xor(sq,o,64); sq2+=__shfl_xor(sq2,o,64); }
      float m_ = sq*(1.f/32.f);
      float rs = rsqrtf(sq2*(1.f/32.f)-m_*m_+1e-5f);
      unsigned short h0,l0,h1,l1;
      sp2((ev0-m_)*rs, h0, l0);
      sp2((ev1-m_)*rs, h1, l1);
      int r = 4*kg+q;
      Yhw[r*104 + n]    = h0;
      Yhw[r*104 + 16+n] = h1;
      Ylw[r*104 + n]    = l0;
      Ylw[r*104 + 16+n] = l1;
    }

    // ---- hid = relu(e2 @ Wm1cf + nodeA_i + (bm1f+nodeBj) + dist*wm1d); H overlaid in Y cols 0..63 ----
    short8v e2Ah = *(const short8v*)&Yhw[n*104 + kg*8];
    short8v e2Al = *(const short8v*)&Ylw[n*104 + kg*8];
    float dist_q[4];
    #pragma unroll
    for(int q=0;q<4;q++) dist_q[q] = __shfl(dist_r, 4*kg+q, 64);
    #pragma unroll
    for(int nt=0;nt<4;nt++){
      short8v wlo = *(const short8v*)&WloE[(14+nt)*512 + lane*8];
      f32x4 hacc = {0.f,0.f,0.f,0.f};
      hacc = __builtin_amdgcn_mfma_f32_16x16x32_bf16(e2Ah, wf[14+nt], hacc, 0,0,0);
      hacc = __builtin_amdgcn_mfma_f32_16x16x32_bf16(e2Al, wf[14+nt], hacc, 0,0,0);
      hacc = __builtin_amdgcn_mfma_f32_16x16x32_bf16(e2Ah, wlo,       hacc, 0,0,0);
      #pragma unroll
      for(int q=0;q<4;q++){
        float t_ = hacc[q] + bm1n[nt] + dist_q[q]*wm1d[nt] + na[nt][q];
        float hv = fmaxf(t_,0.f);
        unsigned short h_, l_;
        sp2(hv, h_, l_);
        Yhw[(4*kg+q)*104 + nt*16+n] = h_;
        Ylw[(4*kg+q)*104 + nt*16+n] = l_;
      }
    }

    // ---- m = relu(hid @ Wm2f + bm2) ----
    short8v hAh[2], hAl[2];
    #pragma unroll
    for(int kt=0;kt<2;kt++){
      hAh[kt] = *(const short8v*)&Yhw[n*104 + kt*32 + kg*8];
      hAl[kt] = *(const short8v*)&Ylw[n*104 + kt*32 + kg*8];
    }
    f32x4 ma0={0.f,0.f,0.f,0.f}, ma1={0.f,0.f,0.f,0.f};
    #pragma unroll
    for(int kt=0;kt<2;kt++){
      short8v wlo0 = *(const short8v*)&WloE[(18+2*kt)*512 + lane*8];
      short8v wlo1 = *(const short8v*)&WloE[(19+2*kt)*512 + lane*8];
      ma0 = __builtin_amdgcn_mfma_f32_16x16x32_bf16(hAh[kt], wf[18+2*kt], ma0, 0,0,0);
      ma0 = __builtin_amdgcn_mfma_f32_16x16x32_bf16(hAl[kt], wf[18+2*kt], ma0, 0,0,0);
      ma0 = __builtin_amdgcn_mfma_f32_16x16x32_bf16(hAh[kt], wlo0,       ma0, 0,0,0);
      ma1 = __builtin_amdgcn_mfma_f32_16x16x32_bf16(hAh[kt], wf[19+2*kt], ma1, 0,0,0);
      ma1 = __builtin_amdgcn_mfma_f32_16x16x32_bf16(hAl[kt], wf[19+2*kt], ma1, 0,0,0);
      ma1 = __builtin_amdgcn_mfma_f32_16x16x32_bf16(hAh[kt], wlo1,       ma1, 0,0,0);
    }
    #pragma unroll
    for(int q=0;q<4;q++){
      float mv0 = fmaxf(ma0[q]+bm2r0, 0.f);
      float mv1 = fmaxf(ma1[q]+bm2r1, 0.f);
      accM0 += mk[q]*mv0;
      accM1 += mk[q]*mv1;
      unsigned short h0,l0,h1,l1;
      sp2(mv0, h0, l0);
      sp2(mv1, h1, l1);
      int r = 4*kg+q;
      Yhw[r*104 + n]    = h0;
      Yhw[r*104 + 16+n] = h1;
      Ylw[r*104 + n]    = l0;
      Ylw[r*104 + 16+n] = l1;
    }

    // ---- coef = m @ Wcf + bc ----
    short8v mAh = *(const short8v*)&Yhw[n*104 + kg*8];
    short8v mAl = *(const short8v*)&Ylw[n*104 + kg*8];
    short8v wloC = *(const short8v*)&WloE[22*512 + lane*8];
    f32x4 cf = {0.f,0.f,0.f,0.f};
    cf = __builtin_amdgcn_mfma_f32_16x16x32_bf16(mAh, wf[22], cf, 0,0,0);
    cf = __builtin_amdgcn_mfma_f32_16x16x32_bf16(mAl, wf[22], cf, 0,0,0);
    cf = __builtin_amdgcn_mfma_f32_16x16x32_bf16(mAh, wloC,  cf, 0,0,0);
    if(n<8){
      #pragma unroll
      for(int q=0;q<4;q++) CT[(4*kg+q)*8+n] = cf[q]+bcr;
    }
    f32x4 cA = *(const f32x4*)&CT[n*8];
    f32x4 cB = *(const f32x4*)&CT[n*8+4];

    // ---- vmsg accumulation for row (i0+n) ----
    accV[0] += mkr*(cA[0]*dxr + cA[1]*v00 + cA[2]*v10 + cA[3]*v20);
    accV[1] += mkr*(cA[0]*dyr + cA[1]*v01 + cA[2]*v11 + cA[3]*v21);
    accV[2] += mkr*(cA[0]*dzr + cA[1]*v02 + cA[2]*v12 + cA[3]*v22);
    accV[3] += mkr*(cB[0]*dxr + cB[1]*v00 + cB[2]*v10 + cB[3]*v20);
    accV[4] += mkr*(cB[0]*dyr + cB[1]*v01 + cB[2]*v11 + cB[3]*v21);
    accV[5] += mkr*(cB[0]*dzr + cB[1]*v02 + cB[2]*v12 + cB[3]*v22);

    // ---- rotate prefetched row in ----
    if(hasNext){
      #pragma unroll
      for(int kt=0;kt<4;kt++)
        #pragma unroll
        for(int e=0;e<8;e++) x[kt][e] = xn[kt][e];
    }
  }

  // ---- reductions ----
  accM0 += __shfl_xor(accM0,16,64); accM0 += __shfl_xor(accM0,32,64);
  accM1 += __shfl_xor(accM1,16,64); accM1 += __shfl_xor(accM1,32,64);
  #pragma unroll
  for(int c=0;c<6;c++){
    #pragma unroll
    for(int o=8;o;o>>=1) accV[c] += __shfl_xor(accV[c],o,64);
  }
  if(lane<16){ redM[wave][n] = accM0; redM[wave][16+n] = accM1; }
  if(lane==0){
    #pragma unroll
    for(int c=0;c<6;c++) redV[wave][c]=accV[c];
  }
  __syncthreads();
  if(tid<32) aggM[j*32+tid] = redM[0][tid]+redM[1][tid]+redM[2][tid]+redM[3][tid];
  if(tid>=64 && tid<70){
    int c = tid-64;
    aggV[j*6+c] = redV[0][c]+redV[1][c]+redV[2][c]+redV[3][c];
  }
}

// ---------------- K7: state_out + SE(3) frame update ----------------
__global__ void k_final(const float* __restrict__ node, const float* __restrict__ aggM,
                        const float* __restrict__ aggV, const float* __restrict__ Wh,
                        const float* __restrict__ bh, const float* __restrict__ Wv,
                        const float* __restrict__ ca, const float* __restrict__ vvb,
                        float* __restrict__ out){
  int l = blockIdx.x, lane = threadIdx.x;
  if(lane<16){
    float acc = bh[lane];
    for(int c=0;c<32;c++) acc += node[l*32+c]*Wh[c*16+lane];
    for(int c=0;c<32;c++) acc += aggM[l*32+c]*Wh[(32+c)*16+lane];
    out[4608 + l*16 + lane] = acc;
  }
  if(lane<9){
    int a = lane/3, vd = lane%3;
    float T[3], R[3];
    for(int q2=0;q2<3;q2++){
      float v0 = vvb[l*9+q2], v1 = vvb[l*9+3+q2], v2 = vvb[l*9+6+q2];
      T[q2] = aggV[l*6+q2]   + Wv[0]*v0 + Wv[1]*v1 + Wv[2]*v2;
      R[q2] = aggV[l*6+3+q2] + Wv[3]*v0 + Wv[4]*v1 + Wv[5]*v2;
    }
    float ang = sqrtf(R[0]*R[0]+R[1]*R[1]+R[2]*R[2]);
    float inv = 1.f/(ang+1e-5f);
    float Rv0=R[0]*inv, Rv1=R[1]*inv, Rv2=R[2]*inv;
    float va0=vvb[l*9+a*3+0], va1=vvb[l*9+a*3+1], va2=vvb[l*9+a*3+2];
    float Rdv = Rv0*va0+Rv1*va1+Rv2*va2;
    float Rvv[3]={Rv0,Rv1,Rv2};
    float vaa[3]={va0,va1,va2};
    float Rxv = Rvv[(vd+1)%3]*vaa[(vd+2)%3] - Rvv[(vd+2)%3]*vaa[(vd+1)%3];
    float vperp = vaa[vd] - Rvv[vd]*Rdv;
    float upar  = Rvv[vd]*Rdv;
    float cc = cosf(ang), ss = sinf(ang);
    float vnew = vperp*cc + Rxv*ss + upar;
    out[l*9+a*3+vd] = vnew + ca[l*3+vd] + T[vd];
  }
}

extern "C" void kernel_launch(void* const* d_in, const int* in_sizes, int n_in,
                              void* d_out, int out_size, void* d_ws, size_t ws_size,
                              hipStream_t stream) {
  const float* msa    = (const float*)d_in[0];
  const float* pair   = (const float*)d_in[1];
  const float* xyz    = (const float*)d_in[2];
  const float* state  = (const float*)d_in[3];
  const float* seq1hot= (const float*)d_in[4];
  const int*   idx    = (const int*)d_in[5];
  const int*   topk   = (const int*)d_in[6];
  const float* g_msa  = (const float*)d_in[7];  const float* b_msa  = (const float*)d_in[8];
  const float* g_pair = (const float*)d_in[9];  const float* b_pair = (const float*)d_in[10];
  const float* g_state= (const float*)d_in[11]; const float* b_state= (const float*)d_in[12];
  const float* Wq = (const float*)d_in[13]; const float* bq = (const float*)d_in[14];
  const float* Wk = (const float*)d_in[15]; const float* bk = (const float*)d_in[16];
  const float* Wx = (const float*)d_in[17]; const float* bx = (const float*)d_in[18];
  const float* We1= (const float*)d_in[19]; const float* be1= (const float*)d_in[20];
  const float* We2= (const float*)d_in[21]; const float* be2= (const float*)d_in[22];
  const float* g_node=(const float*)d_in[23]; const float* b_node=(const float*)d_in[24];
  const float* g_e1 = (const float*)d_in[25]; const float* b_e1 = (const float*)d_in[26];
  const float* g_e2 = (const float*)d_in[27]; const float* b_e2 = (const float*)d_in[28];
  const float* Wm1= (const float*)d_in[29]; const float* bm1= (const float*)d_in[30];
  const float* Wm2= (const float*)d_in[31]; const float* bm2= (const float*)d_in[32];
  const float* Wc = (const float*)d_in[33]; const float* bc = (const float*)d_in[34];
  const float* Wh = (const float*)d_in[35]; const float* bh = (const float*)d_in[36];
  const float* Wv = (const float*)d_in[37];
  float* out = (float*)d_out;

  float* ws = (float*)d_ws;
  float* node   = ws; ws += 512*32;
  float* nodeA  = ws; ws += 512*64;
  float* nodeB  = ws; ws += 512*64;
  float* cab    = ws; ws += 512*3;
  float* vvb    = ws; ws += 512*9;
  float* aggM   = ws; ws += 512*32;
  float* aggV   = ws; ws += 512*6;
  float* bbuf   = ws; ws += 160;
  unsigned short* wbuf = (unsigned short*)ws; ws += (46*512)/2 + 8;
  unsigned char* maskT = (unsigned char*)ws;

  k_fold<<<48,512,0,stream>>>(We1,be1,g_pair,b_pair,We2,be2,g_e1,b_e1,Wm1,bm1,g_e2,b_e2,Wm2,Wc,
                              xyz,wbuf,bbuf,cab,vvb);
  k_ctx<<<512,256,0,stream>>>(msa,g_msa,b_msa,Wq,bq,Wk,bk,seq1hot,state,g_state,b_state,
                              Wx,bx,g_node,b_node,Wm1,node,nodeA,nodeB,cab,idx,topk,maskT);
  k_pair_mfma<<<512,256,0,stream>>>(pair,wbuf,bbuf,Wm1,bm2,bc,nodeA,nodeB,cab,vvb,idx,maskT,aggM,aggV);
  k_final<<<512,64,0,stream>>>(node,aggM,aggV,Wh,bh,Wv,cab,vvb,out);
}

// Round 13
// 106.399 us; speedup vs baseline: 1.9165x; 1.0636x over previous
//
#include <hip/hip_runtime.h>
#include <hip/hip_bf16.h>

typedef __attribute__((ext_vector_type(8))) short short8v;
typedef __attribute__((ext_vector_type(4))) float f32x4;

__device__ __forceinline__ unsigned short f2bu(float a){
  union { __hip_bfloat16 b; unsigned short u; } cv;
  cv.b = __float2bfloat16(a);
  return cv.u;
}
// split: a = hi + lo (hi,lo bf16). Residual construction is exact for any rounding mode.
__device__ __forceinline__ void sp2(float a, unsigned short &h, unsigned short &l){
  h = f2bu(a);
  l = f2bu(a - __uint_as_float(((unsigned)h)<<16));
}
__device__ __forceinline__ float wred64(float v){
  #pragma unroll
  for(int o=32;o;o>>=1) v += __shfl_xor(v,o,64);
  return v;
}
__device__ __forceinline__ float wred32(float v){
  #pragma unroll
  for(int o=16;o;o>>=1) v += __shfl_xor(v,o,64);
  return v;
}
__device__ __forceinline__ float wmax64(float v){
  #pragma unroll
  for(int o=32;o;o>>=1) v = fmaxf(v,__shfl_xor(v,o,64));
  return v;
}

// ---------------- K1: fused ctx (blocks 0..511) + fold/biases/ca,vv (blocks 512..559) ----------------
__global__ void __launch_bounds__(256) k_ctx(
  const float* __restrict__ msa, const float* __restrict__ g_msa, const float* __restrict__ b_msa,
  const float* __restrict__ Wq, const float* __restrict__ bq,
  const float* __restrict__ Wk, const float* __restrict__ bk,
  const float* __restrict__ seq1hot, const float* __restrict__ state,
  const float* __restrict__ g_state, const float* __restrict__ b_state,
  const float* __restrict__ Wx, const float* __restrict__ bx,
  const float* __restrict__ g_node, const float* __restrict__ b_node,
  const float* __restrict__ Wm1, const float* __restrict__ xyz,
  const int* __restrict__ idx, const int* __restrict__ topk_ptr,
  const float* __restrict__ We1, const float* __restrict__ be1,
  const float* __restrict__ g_pair, const float* __restrict__ b_pair,
  const float* __restrict__ We2, const float* __restrict__ be2,
  const float* __restrict__ g_e1, const float* __restrict__ b_e1,
  const float* __restrict__ bm1, const float* __restrict__ g_e2, const float* __restrict__ b_e2,
  const float* __restrict__ Wm2, const float* __restrict__ Wc,
  float* __restrict__ node, float* __restrict__ nodeA, float* __restrict__ nodeB,
  unsigned char* __restrict__ maskT,
  unsigned short* __restrict__ wbuf, float* __restrict__ bbuf,
  float* __restrict__ ca, float* __restrict__ vv)
{
  int tid = threadIdx.x;

  // ---------- fold / biases / ca,vv part ----------
  if(blockIdx.x >= 512){
    int fidx = blockIdx.x - 512;   // 0..47
    if(fidx < 46){
      for(int tt=tid; tt<512; tt+=256){
        int t = fidx*512 + tt;
        int lane = tt>>3, e = tt&7;
        int f = (fidx<23)? fidx : fidx-23;
        int krow = (lane>>4)*8 + e;
        int n = lane&15;
        float val = 0.f;
        if(f<8){
          int kt=f>>1, nt=f&1; int c=kt*32+krow, d=nt*16+n;
          val = g_pair[c]*We1[c*32+d];
        } else if(f<14){
          int f2=f-8; int kt=f2>>1, nt=f2&1; int c=kt*32+krow, d=nt*16+n;
          if(c<32)      val = g_e1[c]*We2[c*32+d];
          else if(c<69) val = We2[c*32+d];
          else          val = 0.f;
        } else if(f<18){
          int nt=f-14; int c=krow, h=nt*16+n;
          val = g_e2[c]*Wm1[(64+c)*64+h];
        } else if(f<22){
          int f2=f-18; int kt=f2>>1, nt=f2&1; int c=kt*32+krow, d=nt*16+n;
          val = Wm2[c*32+d];
        } else {
          int c=krow;
          val = (n<8)? Wc[c*8+n] : 0.f;
        }
        unsigned short h = f2bu(val);
        if(fidx<23) wbuf[t] = h;
        else {
          float fh = __uint_as_float(((unsigned)h)<<16);
          wbuf[t] = f2bu(val - fh);
        }
      }
    } else if(fidx == 46){
      if(tid<32){
        float s = be1[tid];
        for(int c=0;c<128;c++) s += b_pair[c]*We1[c*32+tid];
        bbuf[tid]=s;
      } else if(tid<64){
        int d=tid-32; float s=be2[d];
        for(int c=0;c<32;c++) s += b_e1[c]*We2[c*32+d];
        bbuf[tid]=s;
      } else if(tid<128){
        int h=tid-64; float s=bm1[h];
        for(int c=0;c<32;c++) s += b_e2[c]*Wm1[(64+c)*64+h];
        bbuf[tid]=s;
      }
    } else {
      for(int l=tid; l<512; l+=256){
        float c0=xyz[l*9+3], c1=xyz[l*9+4], c2=xyz[l*9+5];
        ca[l*3+0]=c0; ca[l*3+1]=c1; ca[l*3+2]=c2;
        #pragma unroll
        for(int a2=0;a2<3;a2++){
          vv[l*9+a2*3+0]=xyz[l*9+a2*3+0]-c0;
          vv[l*9+a2*3+1]=xyz[l*9+a2*3+1]-c1;
          vv[l*9+a2*3+2]=xyz[l*9+a2*3+2]-c2;
        }
      }
    }
    return;
  }

  // ---------- ctx part (block per l) ----------
  int l = blockIdx.x;
  int wave = tid>>6, lane = tid&63;
  __shared__ float ms[64][64];
  __shared__ float qs[64];
  __shared__ float logit[64];
  __shared__ float part[4][64];
  __shared__ float ins[101];
  __shared__ float nd[32];

  // fused msa layernorm: 4 threads per row (shfl_xor 1,2 stay in group)
  {
    int nn = tid>>2, qd = tid&3;
    const float* mrow = msa + ((size_t)nn*512 + (size_t)l)*64 + qd*16;
    f32x4 a[4];
    #pragma unroll
    for(int t=0;t<4;t++) a[t] = *(const f32x4*)(mrow + t*4);
    float s=0.f, ss=0.f;
    #pragma unroll
    for(int t=0;t<4;t++)
      #pragma unroll
      for(int e=0;e<4;e++){ float v=a[t][e]; s+=v; ss+=v*v; }
    s  += __shfl_xor(s,1,64);  s  += __shfl_xor(s,2,64);
    ss += __shfl_xor(ss,1,64); ss += __shfl_xor(ss,2,64);
    float mu = s*(1.f/64.f);
    float rstd = rsqrtf(ss*(1.f/64.f) - mu*mu + 1e-5f);
    #pragma unroll
    for(int t=0;t<4;t++){
      f32x4 g4 = *(const f32x4*)(g_msa + qd*16 + t*4);
      f32x4 b4 = *(const f32x4*)(b_msa + qd*16 + t*4);
      f32x4 o4;
      #pragma unroll
      for(int e=0;e<4;e++) o4[e] = (a[t][e]-mu)*rstd*g4[e] + b4[e];
      *(f32x4*)&ms[nn][qd*16 + t*4] = o4;
    }
  }
  __syncthreads();
  if(wave==0){
    float acc = bq[lane];
    for(int k=0;k<64;k++) acc += ms[0][k]*Wq[k*64+lane];
    qs[lane] = acc*0.125f;
  }
  __syncthreads();
  float qd2 = qs[lane];
  for(int it=0; it<16; ++it){
    int nn = it*4 + wave;
    float acc = bk[lane];
    for(int k2=0;k2<64;k2++) acc += ms[nn][k2]*Wk[k2*64+lane];
    float p = wred64(qd2*acc);
    if(lane==0) logit[nn] = p;
  }
  __syncthreads();
  float v  = logit[lane];
  float mx = wmax64(v);
  float e  = expf(v-mx);
  float sd = wred64(e);
  float a  = e/sd;
  float pm = 0.f;
  for(int it=0; it<16; ++it){
    int nn = it*4 + wave;
    pm += __shfl(a,nn,64)*ms[nn][lane];
  }
  part[wave][lane] = pm;
  __syncthreads();
  if(wave==0){
    ins[lane] = part[0][lane]+part[1][lane]+part[2][lane]+part[3][lane];
    if(lane<21) ins[64+lane] = seq1hot[l*21+lane];
    float sv = (lane<16)? state[l*16+lane] : 0.f;
    float mu = sv;
    #pragma unroll
    for(int o=8;o;o>>=1) mu += __shfl_xor(mu,o,64);
    mu *= (1.f/16.f);
    float dv = sv-mu;
    float var = dv*dv;
    #pragma unroll
    for(int o=8;o;o>>=1) var += __shfl_xor(var,o,64);
    var *= (1.f/16.f);
    if(lane<16) ins[85+lane] = dv*rsqrtf(var+1e-5f)*g_state[lane]+b_state[lane];

    int d = lane & 31;
    float np_ = 0.f;
    if(lane<32){
      np_ = bx[d];
      for(int c=0;c<101;c++) np_ += ins[c]*Wx[c*32+d];
    }
    float mu2 = wred32(np_)*(1.f/32.f);
    float d2  = np_-mu2;
    float v2  = wred32(d2*d2)*(1.f/32.f);
    float nv  = d2*rsqrtf(v2+1e-5f);
    if(lane<32){
      nv = nv*g_node[d]+b_node[d];
      node[l*32+d] = nv;
      nd[d] = nv;
    }
    float a2=0.f, b2=0.f;
    for(int c=0;c<32;c++){
      float x = nd[c];
      a2 += x*Wm1[c*64+lane];
      b2 += x*Wm1[(32+c)*64+lane];
    }
    nodeA[l*64+lane] = a2;
    nodeB[l*64+lane] = b2;
  } else if(wave==1){
    // ---- top-k mask for row l (ca read directly from xyz; no cross-block dependence) ----
    int i = l;
    float cx = xyz[i*9+3], cy = xyz[i*9+4], cz = xyz[i*9+5];
    int idxi = idx[i];
    unsigned long long key[8];
    #pragma unroll
    for(int t=0;t<8;t++){
      int jj = t*64 + lane;
      float dx = cx-xyz[jj*9+3], dy = cy-xyz[jj*9+4], dz = cz-xyz[jj*9+5];
      float dd = sqrtf(fmaxf(dx*dx+dy*dy+dz*dz, 1e-12f));
      if(jj==i) dd += 999.9f;
      key[t] = (((unsigned long long)__float_as_uint(dd))<<32) | (unsigned)jj;
      int sep = abs(idx[jj]-idxi);
      maskT[jj*512+i] = (jj!=i && sep<9) ? 1 : 0;
    }
    int kk = *topk_ptr; if(kk>512) kk = 512;
    for(int t=0;t<kk;t++){
      unsigned long long m = key[0];
      #pragma unroll
      for(int u=1;u<8;u++) m = (key[u]<m)? key[u] : m;
      #pragma unroll
      for(int o=32;o;o>>=1){
        unsigned long long o2 = __shfl_xor(m,o,64);
        m = (o2<m)? o2 : m;
      }
      int jc = (int)(m & 0xffffffffu);
      if(lane==0) maskT[jc*512+i] = 1;
      #pragma unroll
      for(int u=0;u<8;u++) if(key[u]==m) key[u] = ~0ull;
    }
  }
}

// ---------------- K2: per-pair MLP (R12 loop) + fused k_final epilogue ----------------
__global__ void __launch_bounds__(256,2) k_pair_mfma(
  const float* __restrict__ pair, const unsigned short* __restrict__ wbuf,
  const float* __restrict__ bbuf, const float* __restrict__ Wm1,
  const float* __restrict__ bm2, const float* __restrict__ bc,
  const float* __restrict__ nodeA, const float* __restrict__ nodeB,
  const float* __restrict__ node,
  const float* __restrict__ ca, const float* __restrict__ vv,
  const int* __restrict__ idx, const unsigned char* __restrict__ maskT,
  const float* __restrict__ Wh, const float* __restrict__ bh,
  const float* __restrict__ Wv, float* __restrict__ out)
{
  const int j = blockIdx.x, tid = threadIdx.x;
  const int wave = tid>>6, lane = tid&63;
  const int kg = lane>>4, n = lane&15;

  __shared__ __align__(16) unsigned short Yh[4][16*104];
  __shared__ __align__(16) unsigned short Yl[4][16*104];
  __shared__ __align__(16) unsigned short WloE[23*512];
  __shared__ float coefT[4][16*8];
  __shared__ float redM[4][32];
  __shared__ float redV[4][8];
  __shared__ float aggMs[32];
  __shared__ float aggVs[6];
  unsigned short* Yhw = Yh[wave];
  unsigned short* Ylw = Yl[wave];
  float* CT = coefT[wave];

  for(int t=tid; t<(23*512)/8; t+=256)
    ((uint4*)WloE)[t] = ((const uint4*)(wbuf + 23*512))[t];

  // hi weight fragments in VGPRs
  short8v wf[23];
  #pragma unroll
  for(int f=0; f<23; f++) wf[f] = *(const short8v*)(wbuf + f*512 + lane*8);

  const float be1f0 = bbuf[n],     be1f1 = bbuf[16+n];
  const float be2f0 = bbuf[32+n],  be2f1 = bbuf[48+n];
  float bm1n[4], wm1d[4];
  #pragma unroll
  for(int nt=0;nt<4;nt++){
    bm1n[nt] = bbuf[64+nt*16+n] + nodeB[j*64+nt*16+n];   // bm1f + nodeBj folded
    wm1d[nt] = Wm1[96*64+nt*16+n];
  }
  const float bm2r0 = bm2[n], bm2r1 = bm2[16+n];
  const float bcr = (n<8)? bc[n] : 0.f;
  const float cjx = ca[j*3], cjy = ca[j*3+1], cjz = ca[j*3+2];
  const int idxj = idx[j];

  __syncthreads();   // WloE staged

  // zero pad cols 69..95 once (hid occupies only 0..63, never clobbers)
  for(int t=lane; t<16*27; t+=64){ int r=t/27, c=69+t-r*27; Yhw[r*104+c]=0; Ylw[r*104+c]=0; }

  float accM0=0.f, accM1=0.f;
  float accV[6]={0.f,0.f,0.f,0.f,0.f,0.f};

  // ---- preload first pair row (i = wave*16 + n) ----
  float x[4][8];
  {
    const float* prow0 = pair + (((size_t)(wave*16+n))*512 + (size_t)j)*128;
    #pragma unroll
    for(int kt=0;kt<4;kt++){
      *(f32x4*)&x[kt][0] = *(const f32x4*)(prow0 + kt*32 + kg*8);
      *(f32x4*)&x[kt][4] = *(const f32x4*)(prow0 + kt*32 + kg*8 + 4);
    }
  }

  for(int i0 = wave*16; i0 < 512; i0 += 64){
    // ---- LN stats in f32 ----
    float s=0.f, ss=0.f;
    #pragma unroll
    for(int kt=0;kt<4;kt++)
      #pragma unroll
      for(int e=0;e<8;e++){ float xv=x[kt][e]; s+=xv; ss+=xv*xv; }
    s  += __shfl_xor(s,16,64);  s  += __shfl_xor(s,32,64);
    ss += __shfl_xor(ss,16,64); ss += __shfl_xor(ss,32,64);
    float mu = s*(1.f/128.f);
    float rstd = rsqrtf(ss*(1.f/128.f) - mu*mu + 1e-5f);

    // ---- prefetch next pair row (T14: issue early, consume at rotate) ----
    float xn[4][8];
    const bool hasNext = (i0+64 < 512);
    if(hasNext){
      const float* prown = pair + (((size_t)(i0+64+n))*512 + (size_t)j)*128;
      #pragma unroll
      for(int kt=0;kt<4;kt++){
        *(f32x4*)&xn[kt][0] = *(const f32x4*)(prown + kt*32 + kg*8);
        *(f32x4*)&xn[kt][4] = *(const f32x4*)(prown + kt*32 + kg*8 + 4);
      }
    }

    // ---- EARLY: issue side-data loads for THIS iteration (consumed in hid/vmsg) ----
    float na[4][4];
    #pragma unroll
    for(int q=0;q<4;q++)
      #pragma unroll
      for(int nt=0;nt<4;nt++)
        na[nt][q] = nodeA[(size_t)(i0+4*kg+q)*64 + nt*16+n];
    float mk[4];
    #pragma unroll
    for(int q=0;q<4;q++) mk[q] = (float)maskT[j*512 + i0+4*kg+q];
    float mkr = (float)maskT[j*512 + i0+n];
    const float* vr = vv + (i0+n)*9;
    float v00=vr[0], v01=vr[1], v02=vr[2];
    float v10=vr[3], v11=vr[4], v12=vr[5];
    float v20=vr[6], v21=vr[7], v22=vr[8];
    const float* cai = ca + (i0+n)*3;
    float cix=cai[0], ciy=cai[1], ciz=cai[2];
    int idxi_r = idx[i0+n];

    // ---- normalize + split hi/lo (VALU work hides the loads above) ----
    short8v xh[4], xl[4];
    #pragma unroll
    for(int kt=0;kt<4;kt++){
      #pragma unroll
      for(int e=0;e<8;e++){
        unsigned short h_, l_;
        sp2((x[kt][e]-mu)*rstd, h_, l_);
        xh[kt][e] = (short)h_;
        xl[kt][e] = (short)l_;
      }
    }

    // ---- e1 = LN(x_hat @ We1f + be1f), split matmul ----
    f32x4 z0={0.f,0.f,0.f,0.f}, z1={0.f,0.f,0.f,0.f};
    #pragma unroll
    for(int kt=0;kt<4;kt++){
      short8v wlo0 = *(const short8v*)&WloE[(2*kt+0)*512 + lane*8];
      short8v wlo1 = *(const short8v*)&WloE[(2*kt+1)*512 + lane*8];
      z0 = __builtin_amdgcn_mfma_f32_16x16x32_bf16(xh[kt], wf[2*kt+0], z0, 0,0,0);
      z0 = __builtin_amdgcn_mfma_f32_16x16x32_bf16(xl[kt], wf[2*kt+0], z0, 0,0,0);
      z0 = __builtin_amdgcn_mfma_f32_16x16x32_bf16(xh[kt], wlo0,      z0, 0,0,0);
      z1 = __builtin_amdgcn_mfma_f32_16x16x32_bf16(xh[kt], wf[2*kt+1], z1, 0,0,0);
      z1 = __builtin_amdgcn_mfma_f32_16x16x32_bf16(xl[kt], wf[2*kt+1], z1, 0,0,0);
      z1 = __builtin_amdgcn_mfma_f32_16x16x32_bf16(xh[kt], wlo1,      z1, 0,0,0);
    }
    #pragma unroll
    for(int q=0;q<4;q++){
      float ev0 = z0[q] + be1f0;
      float ev1 = z1[q] + be1f1;
      float sq  = ev0+ev1;
      float sq2 = ev0*ev0+ev1*ev1;
      #pragma unroll
      for(int o=8;o;o>>=1){ sq+=__shfl_xor(sq,o,64); sq2+=__shfl_xor(sq2,o,64); }
      float m_ = sq*(1.f/32.f);
      float rs = rsqrtf(sq2*(1.f/32.f)-m_*m_+1e-5f);
      unsigned short h0,l0,h1,l1;
      sp2((ev0-m_)*rs, h0, l0);
      sp2((ev1-m_)*rs, h1, l1);
      int r = 4*kg+q;
      Yhw[r*104 + n]    = h0;
      Yhw[r*104 + 16+n] = h1;
      Ylw[r*104 + n]    = l0;
      Ylw[r*104 + 16+n] = l1;
    }

    // ---- dist / rbf / neighbor for row (i0+n) ----
    float dxr = cjx-cix, dyr = cjy-ciy, dzr = cjz-ciz;
    float d2r = dxr*dxr+dyr*dyr+dzr*dzr;
    float dist_r = sqrtf(d2r);
    float drbf = sqrtf(fmaxf(d2r,1e-12f));
    #pragma unroll
    for(int sI=0;sI<9;sI++){
      int t = kg*9+sI;
      float u = (drbf - (float)t*(20.f/35.f))*1.8f;
      unsigned short h_, l_;
      sp2(__expf(-u*u), h_, l_);
      Yhw[n*104 + 32 + t] = h_;
      Ylw[n*104 + 32 + t] = l_;
    }
    if(kg==0){
      int sep = idxj - idxi_r;
      float nb = (sep>=-1 && sep<=1)?(float)sep:0.f;
      unsigned short h_, l_;
      sp2(nb, h_, l_);
      Yhw[n*104 + 68] = h_;
      Ylw[n*104 + 68] = l_;
    }

    // ---- e2 = LN(y @ We2f + be2f) ----
    short8v yh_[3], yl_[3];
    #pragma unroll
    for(int kt=0;kt<3;kt++){
      yh_[kt] = *(const short8v*)&Yhw[n*104 + kt*32 + kg*8];
      yl_[kt] = *(const short8v*)&Ylw[n*104 + kt*32 + kg*8];
    }
    f32x4 e2a0={0.f,0.f,0.f,0.f}, e2a1={0.f,0.f,0.f,0.f};
    #pragma unroll
    for(int kt=0;kt<3;kt++){
      short8v wlo0 = *(const short8v*)&WloE[(8+2*kt)*512 + lane*8];
      short8v wlo1 = *(const short8v*)&WloE[(9+2*kt)*512 + lane*8];
      e2a0 = __builtin_amdgcn_mfma_f32_16x16x32_bf16(yh_[kt], wf[8+2*kt], e2a0, 0,0,0);
      e2a0 = __builtin_amdgcn_mfma_f32_16x16x32_bf16(yl_[kt], wf[8+2*kt], e2a0, 0,0,0);
      e2a0 = __builtin_amdgcn_mfma_f32_16x16x32_bf16(yh_[kt], wlo0,      e2a0, 0,0,0);
      e2a1 = __builtin_amdgcn_mfma_f32_16x16x32_bf16(yh_[kt], wf[9+2*kt], e2a1, 0,0,0);
      e2a1 = __builtin_amdgcn_mfma_f32_16x16x32_bf16(yl_[kt], wf[9+2*kt], e2a1, 0,0,0);
      e2a1 = __builtin_amdgcn_mfma_f32_16x16x32_bf16(yh_[kt], wlo1,      e2a1, 0,0,0);
    }
    #pragma unroll
    for(int q=0;q<4;q++){
      float ev0 = e2a0[q]+be2f0;
      float ev1 = e2a1[q]+be2f1;
      float sq  = ev0+ev1;
      float sq2 = ev0*ev0+ev1*ev1;
      #pragma unroll
      for(int o=8;o;o>>=1){ sq+=__shfl_xor(sq,o,64); sq2+=__shfl_xor(sq2,o,64); }
      float m_ = sq*(1.f/32.f);
      float rs = rsqrtf(sq2*(1.f/32.f)-m_*m_+1e-5f);
      unsigned short h0,l0,h1,l1;
      sp2((ev0-m_)*rs, h0, l0);
      sp2((ev1-m_)*rs, h1, l1);
      int r = 4*kg+q;
      Yhw[r*104 + n]    = h0;
      Yhw[r*104 + 16+n] = h1;
      Ylw[r*104 + n]    = l0;
      Ylw[r*104 + 16+n] = l1;
    }

    // ---- hid = relu(e2 @ Wm1cf + nodeA_i + (bm1f+nodeBj) + dist*wm1d); H overlaid in Y cols 0..63 ----
    short8v e2Ah = *(const short8v*)&Yhw[n*104 + kg*8];
    short8v e2Al = *(const short8v*)&Ylw[n*104 + kg*8];
    float dist_q[4];
    #pragma unroll
    for(int q=0;q<4;q++) dist_q[q] = __shfl(dist_r, 4*kg+q, 64);
    #pragma unroll
    for(int nt=0;nt<4;nt++){
      short8v wlo = *(const short8v*)&WloE[(14+nt)*512 + lane*8];
      f32x4 hacc = {0.f,0.f,0.f,0.f};
      hacc = __builtin_amdgcn_mfma_f32_16x16x32_bf16(e2Ah, wf[14+nt], hacc, 0,0,0);
      hacc = __builtin_amdgcn_mfma_f32_16x16x32_bf16(e2Al, wf[14+nt], hacc, 0,0,0);
      hacc = __builtin_amdgcn_mfma_f32_16x16x32_bf16(e2Ah, wlo,       hacc, 0,0,0);
      #pragma unroll
      for(int q=0;q<4;q++){
        float t_ = hacc[q] + bm1n[nt] + dist_q[q]*wm1d[nt] + na[nt][q];
        float hv = fmaxf(t_,0.f);
        unsigned short h_, l_;
        sp2(hv, h_, l_);
        Yhw[(4*kg+q)*104 + nt*16+n] = h_;
        Ylw[(4*kg+q)*104 + nt*16+n] = l_;
      }
    }

    // ---- m = relu(hid @ Wm2f + bm2) ----
    short8v hAh[2], hAl[2];
    #pragma unroll
    for(int kt=0;kt<2;kt++){
      hAh[kt] = *(const short8v*)&Yhw[n*104 + kt*32 + kg*8];
      hAl[kt] = *(const short8v*)&Ylw[n*104 + kt*32 + kg*8];
    }
    f32x4 ma0={0.f,0.f,0.f,0.f}, ma1={0.f,0.f,0.f,0.f};
    #pragma unroll
    for(int kt=0;kt<2;kt++){
      short8v wlo0 = *(const short8v*)&WloE[(18+2*kt)*512 + lane*8];
      short8v wlo1 = *(const short8v*)&WloE[(19+2*kt)*512 + lane*8];
      ma0 = __builtin_amdgcn_mfma_f32_16x16x32_bf16(hAh[kt], wf[18+2*kt], ma0, 0,0,0);
      ma0 = __builtin_amdgcn_mfma_f32_16x16x32_bf16(hAl[kt], wf[18+2*kt], ma0, 0,0,0);
      ma0 = __builtin_amdgcn_mfma_f32_16x16x32_bf16(hAh[kt], wlo0,       ma0, 0,0,0);
      ma1 = __builtin_amdgcn_mfma_f32_16x16x32_bf16(hAh[kt], wf[19+2*kt], ma1, 0,0,0);
      ma1 = __builtin_amdgcn_mfma_f32_16x16x32_bf16(hAl[kt], wf[19+2*kt], ma1, 0,0,0);
      ma1 = __builtin_amdgcn_mfma_f32_16x16x32_bf16(hAh[kt], wlo1,       ma1, 0,0,0);
    }
    #pragma unroll
    for(int q=0;q<4;q++){
      float mv0 = fmaxf(ma0[q]+bm2r0, 0.f);
      float mv1 = fmaxf(ma1[q]+bm2r1, 0.f);
      accM0 += mk[q]*mv0;
      accM1 += mk[q]*mv1;
      unsigned short h0,l0,h1,l1;
      sp2(mv0, h0, l0);
      sp2(mv1, h1, l1);
      int r = 4*kg+q;
      Yhw[r*104 + n]    = h0;
      Yhw[r*104 + 16+n] = h1;
      Ylw[r*104 + n]    = l0;
      Ylw[r*104 + 16+n] = l1;
    }

    // ---- coef = m @ Wcf + bc ----
    short8v mAh = *(const short8v*)&Yhw[n*104 + kg*8];
    short8v mAl = *(const short8v*)&Ylw[n*104 + kg*8];
    short8v wloC = *(const short8v*)&WloE[22*512 + lane*8];
    f32x4 cf = {0.f,0.f,0.f,0.f};
    cf = __builtin_amdgcn_mfma_f32_16x16x32_bf16(mAh, wf[22], cf, 0,0,0);
    cf = __builtin_amdgcn_mfma_f32_16x16x32_bf16(mAl, wf[22], cf, 0,0,0);
    cf = __builtin_amdgcn_mfma_f32_16x16x32_bf16(mAh, wloC,  cf, 0,0,0);
    if(n<8){
      #pragma unroll
      for(int q=0;q<4;q++) CT[(4*kg+q)*8+n] = cf[q]+bcr;
    }
    f32x4 cA = *(const f32x4*)&CT[n*8];
    f32x4 cB = *(const f32x4*)&CT[n*8+4];

    // ---- vmsg accumulation for row (i0+n) ----
    accV[0] += mkr*(cA[0]*dxr + cA[1]*v00 + cA[2]*v10 + cA[3]*v20);
    accV[1] += mkr*(cA[0]*dyr + cA[1]*v01 + cA[2]*v11 + cA[3]*v21);
    accV[2] += mkr*(cA[0]*dzr + cA[1]*v02 + cA[2]*v12 + cA[3]*v22);
    accV[3] += mkr*(cB[0]*dxr + cB[1]*v00 + cB[2]*v10 + cB[3]*v20);
    accV[4] += mkr*(cB[0]*dyr + cB[1]*v01 + cB[2]*v11 + cB[3]*v21);
    accV[5] += mkr*(cB[0]*dzr + cB[1]*v02 + cB[2]*v12 + cB[3]*v22);

    // ---- rotate prefetched row in ----
    if(hasNext){
      #pragma unroll
      for(int kt=0;kt<4;kt++)
        #pragma unroll
        for(int e=0;e<8;e++) x[kt][e] = xn[kt][e];
    }
  }

  // ---- reductions ----
  accM0 += __shfl_xor(accM0,16,64); accM0 += __shfl_xor(accM0,32,64);
  accM1 += __shfl_xor(accM1,16,64); accM1 += __shfl_xor(accM1,32,64);
  #pragma unroll
  for(int c=0;c<6;c++){
    #pragma unroll
    for(int o=8;o;o>>=1) accV[c] += __shfl_xor(accV[c],o,64);
  }
  if(lane<16){ redM[wave][n] = accM0; redM[wave][16+n] = accM1; }
  if(lane==0){
    #pragma unroll
    for(int c=0;c<6;c++) redV[wave][c]=accV[c];
  }
  __syncthreads();
  if(tid<32) aggMs[tid] = redM[0][tid]+redM[1][tid]+redM[2][tid]+redM[3][tid];
  if(tid>=64 && tid<70){
    int c = tid-64;
    aggVs[c] = redV[0][c]+redV[1][c]+redV[2][c]+redV[3][c];
  }
  __syncthreads();

  // ---- fused k_final epilogue for row j ----
  if(tid<16){
    float acc = bh[tid];
    for(int c=0;c<32;c++) acc += node[j*32+c]*Wh[c*16+tid];
    for(int c=0;c<32;c++) acc += aggMs[c]*Wh[(32+c)*16+tid];
    out[4608 + j*16 + tid] = acc;
  } else if(tid>=32 && tid<41){
    int t2 = tid-32;
    int a = t2/3, vd = t2%3;
    float T[3], R[3];
    for(int q2=0;q2<3;q2++){
      float v0 = vv[j*9+q2], v1 = vv[j*9+3+q2], v2 = vv[j*9+6+q2];
      T[q2] = aggVs[q2]   + Wv[0]*v0 + Wv[1]*v1 + Wv[2]*v2;
      R[q2] = aggVs[3+q2] + Wv[3]*v0 + Wv[4]*v1 + Wv[5]*v2;
    }
    float ang = sqrtf(R[0]*R[0]+R[1]*R[1]+R[2]*R[2]);
    float inv = 1.f/(ang+1e-5f);
    float Rv0=R[0]*inv, Rv1=R[1]*inv, Rv2=R[2]*inv;
    float va0=vv[j*9+a*3+0], va1=vv[j*9+a*3+1], va2=vv[j*9+a*3+2];
    float Rdv = Rv0*va0+Rv1*va1+Rv2*va2;
    float Rvv[3]={Rv0,Rv1,Rv2};
    float vaa[3]={va0,va1,va2};
    float Rxv = Rvv[(vd+1)%3]*vaa[(vd+2)%3] - Rvv[(vd+2)%3]*vaa[(vd+1)%3];
    float vperp = vaa[vd] - Rvv[vd]*Rdv;
    float upar  = Rvv[vd]*Rdv;
    float cc = cosf(ang), ssn = sinf(ang);
    float vnew = vperp*cc + Rxv*ssn + upar;
    out[j*9+a*3+vd] = vnew + ca[j*3+vd] + T[vd];
  }
}

extern "C" void kernel_launch(void* const* d_in, const int* in_sizes, int n_in,
                              void* d_out, int out_size, void* d_ws, size_t ws_size,
                              hipStream_t stream) {
  const float* msa    = (const float*)d_in[0];
  const float* pair   = (const float*)d_in[1];
  const float* xyz    = (const float*)d_in[2];
  const float* state  = (const float*)d_in[3];
  const float* seq1hot= (const float*)d_in[4];
  const int*   idx    = (const int*)d_in[5];
  const int*   topk   = (const int*)d_in[6];
  const float* g_msa  = (const float*)d_in[7];  const float* b_msa  = (const float*)d_in[8];
  const float* g_pair = (const float*)d_in[9];  const float* b_pair = (const float*)d_in[10];
  const float* g_state= (const float*)d_in[11]; const float* b_state= (const float*)d_in[12];
  const float* Wq = (const float*)d_in[13]; const float* bq = (const float*)d_in[14];
  const float* Wk = (const float*)d_in[15]; const float* bk = (const float*)d_in[16];
  const float* Wx = (const float*)d_in[17]; const float* bx = (const float*)d_in[18];
  const float* We1= (const float*)d_in[19]; const float* be1= (const float*)d_in[20];
  const float* We2= (const float*)d_in[21]; const float* be2= (const float*)d_in[22];
  const float* g_node=(const float*)d_in[23]; const float* b_node=(const float*)d_in[24];
  const float* g_e1 = (const float*)d_in[25]; const float* b_e1 = (const float*)d_in[26];
  const float* g_e2 = (const float*)d_in[27]; const float* b_e2 = (const float*)d_in[28];
  const float* Wm1= (const float*)d_in[29]; const float* bm1= (const float*)d_in[30];
  const float* Wm2= (const float*)d_in[31]; const float* bm2= (const float*)d_in[32];
  const float* Wc = (const float*)d_in[33]; const float* bc = (const float*)d_in[34];
  const float* Wh = (const float*)d_in[35]; const float* bh = (const float*)d_in[36];
  const float* Wv = (const float*)d_in[37];
  float* out = (float*)d_out;

  float* ws = (float*)d_ws;
  float* node   = ws; ws += 512*32;
  float* nodeA  = ws; ws += 512*64;
  float* nodeB  = ws; ws += 512*64;
  float* cab    = ws; ws += 512*3;
  float* vvb    = ws; ws += 512*9;
  float* bbuf   = ws; ws += 160;
  unsigned short* wbuf = (unsigned short*)ws; ws += (46*512)/2 + 8;
  unsigned char* maskT = (unsigned char*)ws;

  k_ctx<<<560,256,0,stream>>>(msa,g_msa,b_msa,Wq,bq,Wk,bk,seq1hot,state,g_state,b_state,
                              Wx,bx,g_node,b_node,Wm1,xyz,idx,topk,
                              We1,be1,g_pair,b_pair,We2,be2,g_e1,b_e1,bm1,g_e2,b_e2,Wm2,Wc,
                              node,nodeA,nodeB,maskT,wbuf,bbuf,cab,vvb);
  k_pair_mfma<<<512,256,0,stream>>>(pair,wbuf,bbuf,Wm1,bm2,bc,nodeA,nodeB,node,cab,vvb,idx,maskT,
                                    Wh,bh,Wv,out);
}

// Round 14
// 104.001 us; speedup vs baseline: 1.9607x; 1.0231x over previous
//
#include <hip/hip_runtime.h>
#include <hip/hip_bf16.h>

typedef __attribute__((ext_vector_type(8))) short short8v;
typedef __attribute__((ext_vector_type(4))) float f32x4;

__device__ __forceinline__ unsigned short f2bu(float a){
  union { __hip_bfloat16 b; unsigned short u; } cv;
  cv.b = __float2bfloat16(a);
  return cv.u;
}
// split: a = hi + lo (hi,lo bf16). Residual construction is exact for any rounding mode.
__device__ __forceinline__ void sp2(float a, unsigned short &h, unsigned short &l){
  h = f2bu(a);
  l = f2bu(a - __uint_as_float(((unsigned)h)<<16));
}
__device__ __forceinline__ float wred64(float v){
  #pragma unroll
  for(int o=32;o;o>>=1) v += __shfl_xor(v,o,64);
  return v;
}
__device__ __forceinline__ float wred32(float v){
  #pragma unroll
  for(int o=16;o;o>>=1) v += __shfl_xor(v,o,64);
  return v;
}
__device__ __forceinline__ float wmax64(float v){
  #pragma unroll
  for(int o=32;o;o>>=1) v = fmaxf(v,__shfl_xor(v,o,64));
  return v;
}

// ---------------- K1: fused ctx (blocks 0..511) + fold/biases/ca,vv (blocks 512..559) ----------------
__global__ void __launch_bounds__(256) k_ctx(
  const float* __restrict__ msa, const float* __restrict__ g_msa, const float* __restrict__ b_msa,
  const float* __restrict__ Wq, const float* __restrict__ bq,
  const float* __restrict__ Wk, const float* __restrict__ bk,
  const float* __restrict__ seq1hot, const float* __restrict__ state,
  const float* __restrict__ g_state, const float* __restrict__ b_state,
  const float* __restrict__ Wx, const float* __restrict__ bx,
  const float* __restrict__ g_node, const float* __restrict__ b_node,
  const float* __restrict__ Wm1, const float* __restrict__ xyz,
  const int* __restrict__ idx, const int* __restrict__ topk_ptr,
  const float* __restrict__ We1, const float* __restrict__ be1,
  const float* __restrict__ g_pair, const float* __restrict__ b_pair,
  const float* __restrict__ We2, const float* __restrict__ be2,
  const float* __restrict__ g_e1, const float* __restrict__ b_e1,
  const float* __restrict__ bm1, const float* __restrict__ g_e2, const float* __restrict__ b_e2,
  const float* __restrict__ Wm2, const float* __restrict__ Wc,
  float* __restrict__ node, float* __restrict__ nodeA, float* __restrict__ nodeB,
  unsigned char* __restrict__ maskT,
  unsigned short* __restrict__ wbuf, float* __restrict__ bbuf,
  float* __restrict__ ca, float* __restrict__ vv)
{
  int tid = threadIdx.x;

  // ---------- fold / biases / ca,vv part ----------
  if(blockIdx.x >= 512){
    int fidx = blockIdx.x - 512;   // 0..47
    if(fidx < 46){
      for(int tt=tid; tt<512; tt+=256){
        int t = fidx*512 + tt;
        int lane = tt>>3, e = tt&7;
        int f = (fidx<23)? fidx : fidx-23;
        int krow = (lane>>4)*8 + e;
        int n = lane&15;
        float val = 0.f;
        if(f<8){
          int kt=f>>1, nt=f&1; int c=kt*32+krow, d=nt*16+n;
          val = g_pair[c]*We1[c*32+d];
        } else if(f<14){
          int f2=f-8; int kt=f2>>1, nt=f2&1; int c=kt*32+krow, d=nt*16+n;
          if(c<32)      val = g_e1[c]*We2[c*32+d];
          else if(c<69) val = We2[c*32+d];
          else          val = 0.f;
        } else if(f<18){
          int nt=f-14; int c=krow, h=nt*16+n;
          val = g_e2[c]*Wm1[(64+c)*64+h];
        } else if(f<22){
          int f2=f-18; int kt=f2>>1, nt=f2&1; int c=kt*32+krow, d=nt*16+n;
          val = Wm2[c*32+d];
        } else {
          int c=krow;
          val = (n<8)? Wc[c*8+n] : 0.f;
        }
        unsigned short h = f2bu(val);
        if(fidx<23) wbuf[t] = h;
        else {
          float fh = __uint_as_float(((unsigned)h)<<16);
          wbuf[t] = f2bu(val - fh);
        }
      }
    } else if(fidx == 46){
      if(tid<32){
        float s = be1[tid];
        for(int c=0;c<128;c++) s += b_pair[c]*We1[c*32+tid];
        bbuf[tid]=s;
      } else if(tid<64){
        int d=tid-32; float s=be2[d];
        for(int c=0;c<32;c++) s += b_e1[c]*We2[c*32+d];
        bbuf[tid]=s;
      } else if(tid<128){
        int h=tid-64; float s=bm1[h];
        for(int c=0;c<32;c++) s += b_e2[c]*Wm1[(64+c)*64+h];
        bbuf[tid]=s;
      }
    } else {
      for(int l=tid; l<512; l+=256){
        float c0=xyz[l*9+3], c1=xyz[l*9+4], c2=xyz[l*9+5];
        ca[l*3+0]=c0; ca[l*3+1]=c1; ca[l*3+2]=c2;
        #pragma unroll
        for(int a2=0;a2<3;a2++){
          vv[l*9+a2*3+0]=xyz[l*9+a2*3+0]-c0;
          vv[l*9+a2*3+1]=xyz[l*9+a2*3+1]-c1;
          vv[l*9+a2*3+2]=xyz[l*9+a2*3+2]-c2;
        }
      }
    }
    return;
  }

  // ---------- ctx part (block per l) ----------
  int l = blockIdx.x;
  int wave = tid>>6, lane = tid&63;
  __shared__ float ms[64][64];
  __shared__ float qs[64];
  __shared__ float logit[64];
  __shared__ float part[4][64];
  __shared__ float ins[101];
  __shared__ float nd[32];

  // fused msa layernorm: 4 threads per row (shfl_xor 1,2 stay in group)
  {
    int nn = tid>>2, qd = tid&3;
    const float* mrow = msa + ((size_t)nn*512 + (size_t)l)*64 + qd*16;
    f32x4 a[4];
    #pragma unroll
    for(int t=0;t<4;t++) a[t] = *(const f32x4*)(mrow + t*4);
    float s=0.f, ss=0.f;
    #pragma unroll
    for(int t=0;t<4;t++)
      #pragma unroll
      for(int e=0;e<4;e++){ float v=a[t][e]; s+=v; ss+=v*v; }
    s  += __shfl_xor(s,1,64);  s  += __shfl_xor(s,2,64);
    ss += __shfl_xor(ss,1,64); ss += __shfl_xor(ss,2,64);
    float mu = s*(1.f/64.f);
    float rstd = rsqrtf(ss*(1.f/64.f) - mu*mu + 1e-5f);
    #pragma unroll
    for(int t=0;t<4;t++){
      f32x4 g4 = *(const f32x4*)(g_msa + qd*16 + t*4);
      f32x4 b4 = *(const f32x4*)(b_msa + qd*16 + t*4);
      f32x4 o4;
      #pragma unroll
      for(int e=0;e<4;e++) o4[e] = (a[t][e]-mu)*rstd*g4[e] + b4[e];
      *(f32x4*)&ms[nn][qd*16 + t*4] = o4;
    }
  }
  __syncthreads();
  if(wave==0){
    float acc = bq[lane];
    for(int k=0;k<64;k++) acc += ms[0][k]*Wq[k*64+lane];
    qs[lane] = acc*0.125f;
  }
  __syncthreads();
  float qd2 = qs[lane];
  // logit_n = ms[n]·t + bk·q  where t = Wk·q  (algebraic collapse of the K-projection)
  float t_c = 0.f;
  for(int d=0; d<64; d++) t_c += Wk[lane*64+d]*qs[d];
  float bkq = wred64(bk[lane]*qd2);
  for(int it=0; it<16; ++it){
    int nn = it*4 + wave;
    float p = wred64(ms[nn][lane]*t_c) + bkq;
    if(lane==0) logit[nn] = p;
  }
  __syncthreads();
  float v  = logit[lane];
  float mx = wmax64(v);
  float e  = expf(v-mx);
  float sd = wred64(e);
  float a  = e/sd;
  float pm = 0.f;
  for(int it=0; it<16; ++it){
    int nn = it*4 + wave;
    pm += __shfl(a,nn,64)*ms[nn][lane];
  }
  part[wave][lane] = pm;
  __syncthreads();
  if(wave==0){
    ins[lane] = part[0][lane]+part[1][lane]+part[2][lane]+part[3][lane];
    if(lane<21) ins[64+lane] = seq1hot[l*21+lane];
    float sv = (lane<16)? state[l*16+lane] : 0.f;
    float mu = sv;
    #pragma unroll
    for(int o=8;o;o>>=1) mu += __shfl_xor(mu,o,64);
    mu *= (1.f/16.f);
    float dv = sv-mu;
    float var = dv*dv;
    #pragma unroll
    for(int o=8;o;o>>=1) var += __shfl_xor(var,o,64);
    var *= (1.f/16.f);
    if(lane<16) ins[85+lane] = dv*rsqrtf(var+1e-5f)*g_state[lane]+b_state[lane];

    int d = lane & 31;
    float np_ = 0.f;
    if(lane<32){
      np_ = bx[d];
      for(int c=0;c<101;c++) np_ += ins[c]*Wx[c*32+d];
    }
    float mu2 = wred32(np_)*(1.f/32.f);
    float d2  = np_-mu2;
    float v2  = wred32(d2*d2)*(1.f/32.f);
    float nv  = d2*rsqrtf(v2+1e-5f);
    if(lane<32){
      nv = nv*g_node[d]+b_node[d];
      node[l*32+d] = nv;
      nd[d] = nv;
    }
    float a2=0.f, b2=0.f;
    for(int c=0;c<32;c++){
      float x = nd[c];
      a2 += x*Wm1[c*64+lane];
      b2 += x*Wm1[(32+c)*64+lane];
    }
    nodeA[l*64+lane] = a2;
    nodeB[l*64+lane] = b2;
  } else if(wave==1){
    // ---- top-k mask for row l (ca read directly from xyz; no cross-block dependence) ----
    int i = l;
    float cx = xyz[i*9+3], cy = xyz[i*9+4], cz = xyz[i*9+5];
    int idxi = idx[i];
    unsigned long long key[8];
    #pragma unroll
    for(int t=0;t<8;t++){
      int jj = t*64 + lane;
      float dx = cx-xyz[jj*9+3], dy = cy-xyz[jj*9+4], dz = cz-xyz[jj*9+5];
      float dd = sqrtf(fmaxf(dx*dx+dy*dy+dz*dz, 1e-12f));
      if(jj==i) dd += 999.9f;
      key[t] = (((unsigned long long)__float_as_uint(dd))<<32) | (unsigned)jj;
      int sep = abs(idx[jj]-idxi);
      maskT[jj*512+i] = (jj!=i && sep<9) ? 1 : 0;
    }
    int kk = *topk_ptr; if(kk>512) kk = 512;
    for(int t=0;t<kk;t++){
      unsigned long long m = key[0];
      #pragma unroll
      for(int u=1;u<8;u++) m = (key[u]<m)? key[u] : m;
      #pragma unroll
      for(int o=32;o;o>>=1){
        unsigned long long o2 = __shfl_xor(m,o,64);
        m = (o2<m)? o2 : m;
      }
      int jc = (int)(m & 0xffffffffu);
      if(lane==0) maskT[jc*512+i] = 1;
      #pragma unroll
      for(int u=0;u<8;u++) if(key[u]==m) key[u] = ~0ull;
    }
  }
}

// ---------------- K2: per-pair MLP (R12 loop) + fused k_final epilogue ----------------
__global__ void __launch_bounds__(256,2) k_pair_mfma(
  const float* __restrict__ pair, const unsigned short* __restrict__ wbuf,
  const float* __restrict__ bbuf, const float* __restrict__ Wm1,
  const float* __restrict__ bm2, const float* __restrict__ bc,
  const float* __restrict__ nodeA, const float* __restrict__ nodeB,
  const float* __restrict__ node,
  const float* __restrict__ ca, const float* __restrict__ vv,
  const int* __restrict__ idx, const unsigned char* __restrict__ maskT,
  const float* __restrict__ Wh, const float* __restrict__ bh,
  const float* __restrict__ Wv, float* __restrict__ out)
{
  const int j = blockIdx.x, tid = threadIdx.x;
  const int wave = tid>>6, lane = tid&63;
  const int kg = lane>>4, n = lane&15;

  __shared__ __align__(16) unsigned short Yh[4][16*104];
  __shared__ __align__(16) unsigned short Yl[4][16*104];
  __shared__ __align__(16) unsigned short WloE[23*512];
  __shared__ float coefT[4][16*8];
  __shared__ float redM[4][32];
  __shared__ float redV[4][8];
  __shared__ float aggMs[32];
  __shared__ float aggVs[6];
  unsigned short* Yhw = Yh[wave];
  unsigned short* Ylw = Yl[wave];
  float* CT = coefT[wave];

  for(int t=tid; t<(23*512)/8; t+=256)
    ((uint4*)WloE)[t] = ((const uint4*)(wbuf + 23*512))[t];

  // hi weight fragments in VGPRs
  short8v wf[23];
  #pragma unroll
  for(int f=0; f<23; f++) wf[f] = *(const short8v*)(wbuf + f*512 + lane*8);

  const float be1f0 = bbuf[n],     be1f1 = bbuf[16+n];
  const float be2f0 = bbuf[32+n],  be2f1 = bbuf[48+n];
  float bm1n[4], wm1d[4];
  #pragma unroll
  for(int nt=0;nt<4;nt++){
    bm1n[nt] = bbuf[64+nt*16+n] + nodeB[j*64+nt*16+n];   // bm1f + nodeBj folded
    wm1d[nt] = Wm1[96*64+nt*16+n];
  }
  const float bm2r0 = bm2[n], bm2r1 = bm2[16+n];
  const float bcr = (n<8)? bc[n] : 0.f;
  const float cjx = ca[j*3], cjy = ca[j*3+1], cjz = ca[j*3+2];
  const int idxj = idx[j];

  __syncthreads();   // WloE staged

  // zero pad cols 69..95 once (hid occupies only 0..63, never clobbers)
  for(int t=lane; t<16*27; t+=64){ int r=t/27, c=69+t-r*27; Yhw[r*104+c]=0; Ylw[r*104+c]=0; }

  float accM0=0.f, accM1=0.f;
  float accV[6]={0.f,0.f,0.f,0.f,0.f,0.f};

  // ---- preload first pair row (i = wave*16 + n) ----
  float x[4][8];
  {
    const float* prow0 = pair + (((size_t)(wave*16+n))*512 + (size_t)j)*128;
    #pragma unroll
    for(int kt=0;kt<4;kt++){
      *(f32x4*)&x[kt][0] = *(const f32x4*)(prow0 + kt*32 + kg*8);
      *(f32x4*)&x[kt][4] = *(const f32x4*)(prow0 + kt*32 + kg*8 + 4);
    }
  }

  for(int i0 = wave*16; i0 < 512; i0 += 64){
    // ---- LN stats in f32 ----
    float s=0.f, ss=0.f;
    #pragma unroll
    for(int kt=0;kt<4;kt++)
      #pragma unroll
      for(int e=0;e<8;e++){ float xv=x[kt][e]; s+=xv; ss+=xv*xv; }
    s  += __shfl_xor(s,16,64);  s  += __shfl_xor(s,32,64);
    ss += __shfl_xor(ss,16,64); ss += __shfl_xor(ss,32,64);
    float mu = s*(1.f/128.f);
    float rstd = rsqrtf(ss*(1.f/128.f) - mu*mu + 1e-5f);

    // ---- prefetch next pair row (T14: issue early, consume at rotate) ----
    float xn[4][8];
    const bool hasNext = (i0+64 < 512);
    if(hasNext){
      const float* prown = pair + (((size_t)(i0+64+n))*512 + (size_t)j)*128;
      #pragma unroll
      for(int kt=0;kt<4;kt++){
        *(f32x4*)&xn[kt][0] = *(const f32x4*)(prown + kt*32 + kg*8);
        *(f32x4*)&xn[kt][4] = *(const f32x4*)(prown + kt*32 + kg*8 + 4);
      }
    }

    // ---- EARLY: issue side-data loads for THIS iteration (consumed in hid/vmsg) ----
    float na[4][4];
    #pragma unroll
    for(int q=0;q<4;q++)
      #pragma unroll
      for(int nt=0;nt<4;nt++)
        na[nt][q] = nodeA[(size_t)(i0+4*kg+q)*64 + nt*16+n];
    float mk[4];
    #pragma unroll
    for(int q=0;q<4;q++) mk[q] = (float)maskT[j*512 + i0+4*kg+q];
    float mkr = (float)maskT[j*512 + i0+n];
    const float* vr = vv + (i0+n)*9;
    float v00=vr[0], v01=vr[1], v02=vr[2];
    float v10=vr[3], v11=vr[4], v12=vr[5];
    float v20=vr[6], v21=vr[7], v22=vr[8];
    const float* cai = ca + (i0+n)*3;
    float cix=cai[0], ciy=cai[1], ciz=cai[2];
    int idxi_r = idx[i0+n];

    // ---- normalize + split hi/lo (VALU work hides the loads above) ----
    short8v xh[4], xl[4];
    #pragma unroll
    for(int kt=0;kt<4;kt++){
      #pragma unroll
      for(int e=0;e<8;e++){
        unsigned short h_, l_;
        sp2((x[kt][e]-mu)*rstd, h_, l_);
        xh[kt][e] = (short)h_;
        xl[kt][e] = (short)l_;
      }
    }

    // ---- e1 = LN(x_hat @ We1f + be1f), split matmul ----
    f32x4 z0={0.f,0.f,0.f,0.f}, z1={0.f,0.f,0.f,0.f};
    #pragma unroll
    for(int kt=0;kt<4;kt++){
      short8v wlo0 = *(const short8v*)&WloE[(2*kt+0)*512 + lane*8];
      short8v wlo1 = *(const short8v*)&WloE[(2*kt+1)*512 + lane*8];
      z0 = __builtin_amdgcn_mfma_f32_16x16x32_bf16(xh[kt], wf[2*kt+0], z0, 0,0,0);
      z0 = __builtin_amdgcn_mfma_f32_16x16x32_bf16(xl[kt], wf[2*kt+0], z0, 0,0,0);
      z0 = __builtin_amdgcn_mfma_f32_16x16x32_bf16(xh[kt], wlo0,      z0, 0,0,0);
      z1 = __builtin_amdgcn_mfma_f32_16x16x32_bf16(xh[kt], wf[2*kt+1], z1, 0,0,0);
      z1 = __builtin_amdgcn_mfma_f32_16x16x32_bf16(xl[kt], wf[2*kt+1], z1, 0,0,0);
      z1 = __builtin_amdgcn_mfma_f32_16x16x32_bf16(xh[kt], wlo1,      z1, 0,0,0);
    }
    #pragma unroll
    for(int q=0;q<4;q++){
      float ev0 = z0[q] + be1f0;
      float ev1 = z1[q] + be1f1;
      float sq  = ev0+ev1;
      float sq2 = ev0*ev0+ev1*ev1;
      #pragma unroll
      for(int o=8;o;o>>=1){ sq+=__shfl_xor(sq,o,64); sq2+=__shfl_xor(sq2,o,64); }
      float m_ = sq*(1.f/32.f);
      float rs = rsqrtf(sq2*(1.f/32.f)-m_*m_+1e-5f);
      unsigned short h0,l0,h1,l1;
      sp2((ev0-m_)*rs, h0, l0);
      sp2((ev1-m_)*rs, h1, l1);
      int r = 4*kg+q;
      Yhw[r*104 + n]    = h0;
      Yhw[r*104 + 16+n] = h1;
      Ylw[r*104 + n]    = l0;
      Ylw[r*104 + 16+n] = l1;
    }

    // ---- dist / rbf / neighbor for row (i0+n) ----
    float dxr = cjx-cix, dyr = cjy-ciy, dzr = cjz-ciz;
    float d2r = dxr*dxr+dyr*dyr+dzr*dzr;
    float dist_r = sqrtf(d2r);
    float drbf = sqrtf(fmaxf(d2r,1e-12f));
    #pragma unroll
    for(int sI=0;sI<9;sI++){
      int t = kg*9+sI;
      float u = (drbf - (float)t*(20.f/35.f))*1.8f;
      unsigned short h_, l_;
      sp2(__expf(-u*u), h_, l_);
      Yhw[n*104 + 32 + t] = h_;
      Ylw[n*104 + 32 + t] = l_;
    }
    if(kg==0){
      int sep = idxj - idxi_r;
      float nb = (sep>=-1 && sep<=1)?(float)sep:0.f;
      unsigned short h_, l_;
      sp2(nb, h_, l_);
      Yhw[n*104 + 68] = h_;
      Ylw[n*104 + 68] = l_;
    }

    // ---- e2 = LN(y @ We2f + be2f) ----
    short8v yh_[3], yl_[3];
    #pragma unroll
    for(int kt=0;kt<3;kt++){
      yh_[kt] = *(const short8v*)&Yhw[n*104 + kt*32 + kg*8];
      yl_[kt] = *(const short8v*)&Ylw[n*104 + kt*32 + kg*8];
    }
    f32x4 e2a0={0.f,0.f,0.f,0.f}, e2a1={0.f,0.f,0.f,0.f};
    #pragma unroll
    for(int kt=0;kt<3;kt++){
      short8v wlo0 = *(const short8v*)&WloE[(8+2*kt)*512 + lane*8];
      short8v wlo1 = *(const short8v*)&WloE[(9+2*kt)*512 + lane*8];
      e2a0 = __builtin_amdgcn_mfma_f32_16x16x32_bf16(yh_[kt], wf[8+2*kt], e2a0, 0,0,0);
      e2a0 = __builtin_amdgcn_mfma_f32_16x16x32_bf16(yl_[kt], wf[8+2*kt], e2a0, 0,0,0);
      e2a0 = __builtin_amdgcn_mfma_f32_16x16x32_bf16(yh_[kt], wlo0,      e2a0, 0,0,0);
      e2a1 = __builtin_amdgcn_mfma_f32_16x16x32_bf16(yh_[kt], wf[9+2*kt], e2a1, 0,0,0);
      e2a1 = __builtin_amdgcn_mfma_f32_16x16x32_bf16(yl_[kt], wf[9+2*kt], e2a1, 0,0,0);
      e2a1 = __builtin_amdgcn_mfma_f32_16x16x32_bf16(yh_[kt], wlo1,      e2a1, 0,0,0);
    }
    #pragma unroll
    for(int q=0;q<4;q++){
      float ev0 = e2a0[q]+be2f0;
      float ev1 = e2a1[q]+be2f1;
      float sq  = ev0+ev1;
      float sq2 = ev0*ev0+ev1*ev1;
      #pragma unroll
      for(int o=8;o;o>>=1){ sq+=__shfl_xor(sq,o,64); sq2+=__shfl_xor(sq2,o,64); }
      float m_ = sq*(1.f/32.f);
      float rs = rsqrtf(sq2*(1.f/32.f)-m_*m_+1e-5f);
      unsigned short h0,l0,h1,l1;
      sp2((ev0-m_)*rs, h0, l0);
      sp2((ev1-m_)*rs, h1, l1);
      int r = 4*kg+q;
      Yhw[r*104 + n]    = h0;
      Yhw[r*104 + 16+n] = h1;
      Ylw[r*104 + n]    = l0;
      Ylw[r*104 + 16+n] = l1;
    }

    // ---- hid = relu(e2 @ Wm1cf + nodeA_i + (bm1f+nodeBj) + dist*wm1d); H overlaid in Y cols 0..63 ----
    short8v e2Ah = *(const short8v*)&Yhw[n*104 + kg*8];
    short8v e2Al = *(const short8v*)&Ylw[n*104 + kg*8];
    float dist_q[4];
    #pragma unroll
    for(int q=0;q<4;q++) dist_q[q] = __shfl(dist_r, 4*kg+q, 64);
    #pragma unroll
    for(int nt=0;nt<4;nt++){
      short8v wlo = *(const short8v*)&WloE[(14+nt)*512 + lane*8];
      f32x4 hacc = {0.f,0.f,0.f,0.f};
      hacc = __builtin_amdgcn_mfma_f32_16x16x32_bf16(e2Ah, wf[14+nt], hacc, 0,0,0);
      hacc = __builtin_amdgcn_mfma_f32_16x16x32_bf16(e2Al, wf[14+nt], hacc, 0,0,0);
      hacc = __builtin_amdgcn_mfma_f32_16x16x32_bf16(e2Ah, wlo,       hacc, 0,0,0);
      #pragma unroll
      for(int q=0;q<4;q++){
        float t_ = hacc[q] + bm1n[nt] + dist_q[q]*wm1d[nt] + na[nt][q];
        float hv = fmaxf(t_,0.f);
        unsigned short h_, l_;
        sp2(hv, h_, l_);
        Yhw[(4*kg+q)*104 + nt*16+n] = h_;
        Ylw[(4*kg+q)*104 + nt*16+n] = l_;
      }
    }

    // ---- m = relu(hid @ Wm2f + bm2) ----
    short8v hAh[2], hAl[2];
    #pragma unroll
    for(int kt=0;kt<2;kt++){
      hAh[kt] = *(const short8v*)&Yhw[n*104 + kt*32 + kg*8];
      hAl[kt] = *(const short8v*)&Ylw[n*104 + kt*32 + kg*8];
    }
    f32x4 ma0={0.f,0.f,0.f,0.f}, ma1={0.f,0.f,0.f,0.f};
    #pragma unroll
    for(int kt=0;kt<2;kt++){
      short8v wlo0 = *(const short8v*)&WloE[(18+2*kt)*512 + lane*8];
      short8v wlo1 = *(const short8v*)&WloE[(19+2*kt)*512 + lane*8];
      ma0 = __builtin_amdgcn_mfma_f32_16x16x32_bf16(hAh[kt], wf[18+2*kt], ma0, 0,0,0);
      ma0 = __builtin_amdgcn_mfma_f32_16x16x32_bf16(hAl[kt], wf[18+2*kt], ma0, 0,0,0);
      ma0 = __builtin_amdgcn_mfma_f32_16x16x32_bf16(hAh[kt], wlo0,       ma0, 0,0,0);
      ma1 = __builtin_amdgcn_mfma_f32_16x16x32_bf16(hAh[kt], wf[19+2*kt], ma1, 0,0,0);
      ma1 = __builtin_amdgcn_mfma_f32_16x16x32_bf16(hAl[kt], wf[19+2*kt], ma1, 0,0,0);
      ma1 = __builtin_amdgcn_mfma_f32_16x16x32_bf16(hAh[kt], wlo1,       ma1, 0,0,0);
    }
    #pragma unroll
    for(int q=0;q<4;q++){
      float mv0 = fmaxf(ma0[q]+bm2r0, 0.f);
      float mv1 = fmaxf(ma1[q]+bm2r1, 0.f);
      accM0 += mk[q]*mv0;
      accM1 += mk[q]*mv1;
      unsigned short h0,l0,h1,l1;
      sp2(mv0, h0, l0);
      sp2(mv1, h1, l1);
      int r = 4*kg+q;
      Yhw[r*104 + n]    = h0;
      Yhw[r*104 + 16+n] = h1;
      Ylw[r*104 + n]    = l0;
      Ylw[r*104 + 16+n] = l1;
    }

    // ---- coef = m @ Wcf + bc ----
    short8v mAh = *(const short8v*)&Yhw[n*104 + kg*8];
    short8v mAl = *(const short8v*)&Ylw[n*104 + kg*8];
    short8v wloC = *(const short8v*)&WloE[22*512 + lane*8];
    f32x4 cf = {0.f,0.f,0.f,0.f};
    cf = __builtin_amdgcn_mfma_f32_16x16x32_bf16(mAh, wf[22], cf, 0,0,0);
    cf = __builtin_amdgcn_mfma_f32_16x16x32_bf16(mAl, wf[22], cf, 0,0,0);
    cf = __builtin_amdgcn_mfma_f32_16x16x32_bf16(mAh, wloC,  cf, 0,0,0);
    if(n<8){
      #pragma unroll
      for(int q=0;q<4;q++) CT[(4*kg+q)*8+n] = cf[q]+bcr;
    }
    f32x4 cA = *(const f32x4*)&CT[n*8];
    f32x4 cB = *(const f32x4*)&CT[n*8+4];

    // ---- vmsg accumulation for row (i0+n) ----
    accV[0] += mkr*(cA[0]*dxr + cA[1]*v00 + cA[2]*v10 + cA[3]*v20);
    accV[1] += mkr*(cA[0]*dyr + cA[1]*v01 + cA[2]*v11 + cA[3]*v21);
    accV[2] += mkr*(cA[0]*dzr + cA[1]*v02 + cA[2]*v12 + cA[3]*v22);
    accV[3] += mkr*(cB[0]*dxr + cB[1]*v00 + cB[2]*v10 + cB[3]*v20);
    accV[4] += mkr*(cB[0]*dyr + cB[1]*v01 + cB[2]*v11 + cB[3]*v21);
    accV[5] += mkr*(cB[0]*dzr + cB[1]*v02 + cB[2]*v12 + cB[3]*v22);

    // ---- rotate prefetched row in ----
    if(hasNext){
      #pragma unroll
      for(int kt=0;kt<4;kt++)
        #pragma unroll
        for(int e=0;e<8;e++) x[kt][e] = xn[kt][e];
    }
  }

  // ---- reductions ----
  accM0 += __shfl_xor(accM0,16,64); accM0 += __shfl_xor(accM0,32,64);
  accM1 += __shfl_xor(accM1,16,64); accM1 += __shfl_xor(accM1,32,64);
  #pragma unroll
  for(int c=0;c<6;c++){
    #pragma unroll
    for(int o=8;o;o>>=1) accV[c] += __shfl_xor(accV[c],o,64);
  }
  if(lane<16){ redM[wave][n] = accM0; redM[wave][16+n] = accM1; }
  if(lane==0){
    #pragma unroll
    for(int c=0;c<6;c++) redV[wave][c]=accV[c];
  }
  __syncthreads();
  if(tid<32) aggMs[tid] = redM[0][tid]+redM[1][tid]+redM[2][tid]+redM[3][tid];
  if(tid>=64 && tid<70){
    int c = tid-64;
    aggVs[c] = redV[0][c]+redV[1][c]+redV[2][c]+redV[3][c];
  }
  __syncthreads();

  // ---- fused k_final epilogue for row j ----
  if(tid<16){
    float acc = bh[tid];
    for(int c=0;c<32;c++) acc += node[j*32+c]*Wh[c*16+tid];
    for(int c=0;c<32;c++) acc += aggMs[c]*Wh[(32+c)*16+tid];
    out[4608 + j*16 + tid] = acc;
  } else if(tid>=32 && tid<41){
    int t2 = tid-32;
    int a = t2/3, vd = t2%3;
    float T[3], R[3];
    for(int q2=0;q2<3;q2++){
      float v0 = vv[j*9+q2], v1 = vv[j*9+3+q2], v2 = vv[j*9+6+q2];
      T[q2] = aggVs[q2]   + Wv[0]*v0 + Wv[1]*v1 + Wv[2]*v2;
      R[q2] = aggVs[3+q2] + Wv[3]*v0 + Wv[4]*v1 + Wv[5]*v2;
    }
    float ang = sqrtf(R[0]*R[0]+R[1]*R[1]+R[2]*R[2]);
    float inv = 1.f/(ang+1e-5f);
    float Rv0=R[0]*inv, Rv1=R[1]*inv, Rv2=R[2]*inv;
    float va0=vv[j*9+a*3+0], va1=vv[j*9+a*3+1], va2=vv[j*9+a*3+2];
    float Rdv = Rv0*va0+Rv1*va1+Rv2*va2;
    float Rvv[3]={Rv0,Rv1,Rv2};
    float vaa[3]={va0,va1,va2};
    float Rxv = Rvv[(vd+1)%3]*vaa[(vd+2)%3] - Rvv[(vd+2)%3]*vaa[(vd+1)%3];
    float vperp = vaa[vd] - Rvv[vd]*Rdv;
    float upar  = Rvv[vd]*Rdv;
    float cc = cosf(ang), ssn = sinf(ang);
    float vnew = vperp*cc + Rxv*ssn + upar;
    out[j*9+a*3+vd] = vnew + ca[j*3+vd] + T[vd];
  }
}

extern "C" void kernel_launch(void* const* d_in, const int* in_sizes, int n_in,
                              void* d_out, int out_size, void* d_ws, size_t ws_size,
                              hipStream_t stream) {
  const float* msa    = (const float*)d_in[0];
  const float* pair   = (const float*)d_in[1];
  const float* xyz    = (const float*)d_in[2];
  const float* state  = (const float*)d_in[3];
  const float* seq1hot= (const float*)d_in[4];
  const int*   idx    = (const int*)d_in[5];
  const int*   topk   = (const int*)d_in[6];
  const float* g_msa  = (const float*)d_in[7];  const float* b_msa  = (const float*)d_in[8];
  const float* g_pair = (const float*)d_in[9];  const float* b_pair = (const float*)d_in[10];
  const float* g_state= (const float*)d_in[11]; const float* b_state= (const float*)d_in[12];
  const float* Wq = (const float*)d_in[13]; const float* bq = (const float*)d_in[14];
  const float* Wk = (const float*)d_in[15]; const float* bk = (const float*)d_in[16];
  const float* Wx = (const float*)d_in[17]; const float* bx = (const float*)d_in[18];
  const float* We1= (const float*)d_in[19]; const float* be1= (const float*)d_in[20];
  const float* We2= (const float*)d_in[21]; const float* be2= (const float*)d_in[22];
  const float* g_node=(const float*)d_in[23]; const float* b_node=(const float*)d_in[24];
  const float* g_e1 = (const float*)d_in[25]; const float* b_e1 = (const float*)d_in[26];
  const float* g_e2 = (const float*)d_in[27]; const float* b_e2 = (const float*)d_in[28];
  const float* Wm1= (const float*)d_in[29]; const float* bm1= (const float*)d_in[30];
  const float* Wm2= (const float*)d_in[31]; const float* bm2= (const float*)d_in[32];
  const float* Wc = (const float*)d_in[33]; const float* bc = (const float*)d_in[34];
  const float* Wh = (const float*)d_in[35]; const float* bh = (const float*)d_in[36];
  const float* Wv = (const float*)d_in[37];
  float* out = (float*)d_out;

  float* ws = (float*)d_ws;
  float* node   = ws; ws += 512*32;
  float* nodeA  = ws; ws += 512*64;
  float* nodeB  = ws; ws += 512*64;
  float* cab    = ws; ws += 512*3;
  float* vvb    = ws; ws += 512*9;
  float* bbuf   = ws; ws += 160;
  unsigned short* wbuf = (unsigned short*)ws; ws += (46*512)/2 + 8;
  unsigned char* maskT = (unsigned char*)ws;

  k_ctx<<<560,256,0,stream>>>(msa,g_msa,b_msa,Wq,bq,Wk,bk,seq1hot,state,g_state,b_state,
                              Wx,bx,g_node,b_node,Wm1,xyz,idx,topk,
                              We1,be1,g_pair,b_pair,We2,be2,g_e1,b_e1,bm1,g_e2,b_e2,Wm2,Wc,
                              node,nodeA,nodeB,maskT,wbuf,bbuf,cab,vvb);
  k_pair_mfma<<<512,256,0,stream>>>(pair,wbuf,bbuf,Wm1,bm2,bc,nodeA,nodeB,node,cab,vvb,idx,maskT,
                                    Wh,bh,Wv,out);
}